// Round 4
// baseline (382.138 us; speedup 1.0000x reference)
//
#include <hip/hip_runtime.h>
#include <hip/hip_bf16.h>
#include <cstdint>

#define N_BATCH 2
#define C_IN 256
#define DYN_CH 34
#define CLS_CH 720
#define NUM_CLASSES 80
#define NCOMB 48   // 34 dyn + 4 reg + 10 pad, 3 MFMA n-tiles of 16

typedef __attribute__((ext_vector_type(8))) short short8;   // 8 bf16
typedef __attribute__((ext_vector_type(4))) float f32x4;

typedef const unsigned int __attribute__((address_space(1)))* gas1_t;
typedef unsigned int __attribute__((address_space(3)))* las3_t;

__device__ __forceinline__ void async_ld16(const void* g, void* l) {
  __builtin_amdgcn_global_load_lds((gas1_t)g, (las3_t)l, 16, 0, 0);
}

// --------------------------- pack A (cls): fp32 (N,C,P) -> bf16 tiled [mtile][kcg][row]
__global__ __launch_bounds__(256) void pack_a(
    const float* __restrict__ x, __hip_bfloat16* __restrict__ ap, int P,
    int Mtot) {
  size_t u = (size_t)blockIdx.x * 256 + threadIdx.x;
  int mtile = (int)(u >> 13);
  int rem = (int)(u & 8191);
  int kcg = rem >> 8;
  int row = rem & 255;
  int g = mtile * 256 + row;
  __hip_bfloat16 tmp[8];
  if (g < Mtot) {
    int n = g / P, p = g % P;
    const float* xb = x + (size_t)n * C_IN * P + (size_t)(kcg * 8) * P + p;
#pragma unroll
    for (int c = 0; c < 8; ++c) tmp[c] = __float2bfloat16(xb[(size_t)c * P]);
  } else {
#pragma unroll
    for (int c = 0; c < 8; ++c) tmp[c] = __float2bfloat16(0.f);
  }
  *(uint4*)(ap + u * 8) = *(const uint4*)tmp;
}

// --------------------------- pack row-major (reg): fp32 (N,C,P) -> bf16 [m][256]
__global__ __launch_bounds__(256) void pack_row(
    const float* __restrict__ x, __hip_bfloat16* __restrict__ rp, int P,
    int Mtot) {
  size_t u = (size_t)blockIdx.x * 256 + threadIdx.x;
  int mtile = (int)(u >> 13);
  int rem = (int)(u & 8191);
  int kcg = rem >> 8;
  int row = rem & 255;
  int m = mtile * 256 + row;
  if (m >= Mtot) return;
  int n = m / P, p = m % P;
  const float* xb = x + (size_t)n * C_IN * P + (size_t)(kcg * 8) * P + p;
  __hip_bfloat16 tmp[8];
#pragma unroll
  for (int c = 0; c < 8; ++c) tmp[c] = __float2bfloat16(xb[(size_t)c * P]);
  *((uint4*)rp + (size_t)m * 32 + kcg) = *(const uint4*)tmp;
}

// --------------------------- pack B (cls): cls_w (720,256) -> bf16 [ntile][kcg][och]
__global__ __launch_bounds__(256) void pack_b(
    const float* __restrict__ w, __hip_bfloat16* __restrict__ bp) {
  int u = blockIdx.x * 256 + threadIdx.x;
  if (u >= 9 * 32 * 80) return;
  int ntile = u / 2560;
  int rem = u % 2560;
  int kcg = rem / 80;
  int ochl = rem % 80;
  int och = ntile * 80 + ochl;
  const float* wr = w + (size_t)och * C_IN + kcg * 8;
  __hip_bfloat16 tmp[8];
#pragma unroll
  for (int c = 0; c < 8; ++c) tmp[c] = __float2bfloat16(wr[c]);
  *(uint4*)(bp + (size_t)u * 8) = *(const uint4*)tmp;
}

// -------- pack W (dyn 3x3 + reg 1x1 center-tap): -> bf16 swizzled [chunk j][n][slot s]
__global__ __launch_bounds__(256) void pack_w(
    const float* __restrict__ dyn_w, const float* __restrict__ reg_w,
    __hip_bfloat16* __restrict__ wp) {
  int u = blockIdx.x * 256 + threadIdx.x;  // 18*768 = 13824 units
  if (u >= 13824) return;
  int j = u / 768;
  int r = u % 768;
  int n = r / 16;
  int s = r % 16;
  int ku = j * 16 + (s ^ (n & 7));
  int k0 = ku * 8;
  int tap = k0 >> 8;
  int c0 = k0 & 255;
  __hip_bfloat16 tmp[8];
#pragma unroll
  for (int i = 0; i < 8; ++i) {
    int c = c0 + i;
    float v = 0.f;
    if (n < DYN_CH) v = dyn_w[((size_t)n * C_IN + c) * 9 + tap];
    else if (n < DYN_CH + 4 && tap == 4) v = reg_w[(size_t)(n - DYN_CH) * C_IN + c];
    tmp[i] = __float2bfloat16(v);
  }
  *(uint4*)(wp + (size_t)u * 8) = *(const uint4*)tmp;
}

// ------------------- K2: cls 1x1 bf16 MFMA GEMM -> bf16 map CHANNEL-MAJOR [och][M]
// A-operand = weights (och rows), B-operand = pixels (cols): D[och][px]
__global__ __launch_bounds__(256) void cls_gemm_mfma(
    const uint4* __restrict__ Ap, const uint4* __restrict__ Bp,
    __hip_bfloat16* __restrict__ outT, int Mtot) {
  __shared__ uint4 Ash[1024];
  __shared__ uint4 Bsh[320];
  int tid = threadIdx.x;
  int wave = tid >> 6;
  int lane = tid & 63;
  int l15 = lane & 15;
  int kq = lane >> 4;
  int mtile = blockIdx.x;
  int ntile = blockIdx.y;

  const uint4* Ab = Ap + (size_t)mtile * 8192;
  const uint4* Bb = Bp + (size_t)ntile * 2560;

  f32x4 acc[5][4];  // [och-tile][px-tile]
#pragma unroll
  for (int i = 0; i < 5; ++i)
#pragma unroll
    for (int j = 0; j < 4; ++j) acc[i][j] = (f32x4)0.f;

  for (int kb = 0; kb < 8; ++kb) {
    const uint4* Aslab = Ab + kb * 1024;
#pragma unroll
    for (int i = 0; i < 4; ++i) {
      int j = wave * 4 + i;
      async_ld16(Aslab + j * 64 + lane, &Ash[j * 64]);
    }
    const uint4* Bslab = Bb + kb * 320;
    for (int j = wave; j < 5; j += 4) {
      async_ld16(Bslab + j * 64 + lane, &Bsh[j * 64]);
    }
    __syncthreads();

    short8 a[4], b[5];
    const uint4* Ar = &Ash[kq * 256 + wave * 64 + l15];
#pragma unroll
    for (int mi = 0; mi < 4; ++mi) a[mi] = *(const short8*)&Ar[mi * 16];
    const uint4* Br = &Bsh[kq * 80 + l15];
#pragma unroll
    for (int ni = 0; ni < 5; ++ni) b[ni] = *(const short8*)&Br[ni * 16];
    // D = W * X : A-frag = b (weights), B-frag = a (pixels)
#pragma unroll
    for (int oi = 0; oi < 5; ++oi)
#pragma unroll
      for (int pi = 0; pi < 4; ++pi)
        acc[oi][pi] = __builtin_amdgcn_mfma_f32_16x16x32_bf16(
            b[oi], a[pi], acc[oi][pi], 0, 0, 0);
    __syncthreads();
  }

  // epilogue: D row = och (kq*4+r within oi-tile), col = px (l15 within pi-tile)
  int pxbase = mtile * 256 + wave * 64;
#pragma unroll
  for (int oi = 0; oi < 5; ++oi) {
    int och = ntile * 80 + oi * 16 + kq * 4;
#pragma unroll
    for (int r = 0; r < 4; ++r) {
      __hip_bfloat16* orow = outT + (size_t)(och + r) * Mtot;
#pragma unroll
      for (int pi = 0; pi < 4; ++pi) {
        int px = pxbase + pi * 16 + l15;
        if (px < Mtot) orow[px] = __float2bfloat16(acc[oi][pi][r]);
      }
    }
  }
}

// ---------- K3: dyn3x3 + reg1x1 fused implicit-GEMM MFMA, split-K=3 (tap triples)
__global__ __launch_bounds__(256) void dyn_reg_conv_mfma(
    const uint4* __restrict__ rp, const uint4* __restrict__ wp,
    float* __restrict__ part, int Mtot, int P, int W, int H) {
  __shared__ uint4 Bs[768];  // 48 n x 16 units (12 KB)
  int tid = threadIdx.x;
  int wave = tid >> 6;
  int lane = tid & 63;
  int l15 = lane & 15;
  int kq = lane >> 4;
  int seg = blockIdx.y;

  int m = blockIdx.x * 64 + wave * 16 + l15;
  bool mval = (m < Mtot);
  int mc = mval ? m : 0;
  int n = mc / P;
  int rem = mc - n * P;
  int y = rem / W;
  int x = rem - y * W;

  f32x4 acc[3];
#pragma unroll
  for (int i = 0; i < 3; ++i) acc[i] = (f32x4)0.f;

  for (int jj = 0; jj < 6; ++jj) {
    int j = seg * 6 + jj;
    const uint4* wsrc = wp + (size_t)j * 768 + wave * 192;
#pragma unroll
    for (int i = 0; i < 3; ++i)
      async_ld16(wsrc + i * 64 + lane, &Bs[wave * 192 + i * 64]);

    int tap = j >> 1;
    int cb8 = (j & 1) * 16;
    int dy = tap / 3 - 1, dx = tap % 3 - 1;
    int sy = y + dy, sx = x + dx;
    bool val = mval && ((unsigned)sy < (unsigned)H) && ((unsigned)sx < (unsigned)W);
    size_t srow = (size_t)(m + dy * W + dx);
    uint4 a[4];
#pragma unroll
    for (int t = 0; t < 4; ++t) {
      uint4 v = {0u, 0u, 0u, 0u};
      if (val) v = rp[srow * 32 + cb8 + t * 4 + kq];
      a[t] = v;
    }
    __syncthreads();
#pragma unroll
    for (int t = 0; t < 4; ++t) {
#pragma unroll
      for (int ni = 0; ni < 3; ++ni) {
        int nn = ni * 16 + l15;
        short8 bf = *(const short8*)&Bs[nn * 16 + ((t * 4 + kq) ^ (nn & 7))];
        acc[ni] = __builtin_amdgcn_mfma_f32_16x16x32_bf16(
            *(short8*)&a[t], bf, acc[ni], 0, 0, 0);
      }
    }
    __syncthreads();
  }

  int mrow = blockIdx.x * 64 + wave * 16 + kq * 4;
#pragma unroll
  for (int r = 0; r < 4; ++r) {
    int mm = mrow + r;
    if (mm >= Mtot) continue;
    float* dst = part + ((size_t)seg * Mtot + mm) * NCOMB + l15;
#pragma unroll
    for (int ni = 0; ni < 3; ++ni) dst[ni * 16] = acc[ni][r];
  }
}

// -------------------- bilinear sample of combined-map channel (sums 3 K-segments)
__device__ __forceinline__ float samp48(const float* __restrict__ part,
                                        int Mtot, int nbase, int W, int H,
                                        float px, float py, int ch) {
  float xc = fminf(fmaxf(px, 0.f), (float)(W - 1));
  float yc = fminf(fmaxf(py, 0.f), (float)(H - 1));
  float x0f = floorf(xc), y0f = floorf(yc);
  float fx = xc - x0f, fy = yc - y0f;
  int x0 = (int)x0f, y0 = (int)y0f;
  int x1 = min(x0 + 1, W - 1), y1 = min(y0 + 1, H - 1);
  size_t m00 = (size_t)(nbase + y0 * W + x0);
  size_t m01 = (size_t)(nbase + y0 * W + x1);
  size_t m10 = (size_t)(nbase + y1 * W + x0);
  size_t m11 = (size_t)(nbase + y1 * W + x1);
  float v00 = 0.f, v01 = 0.f, v10 = 0.f, v11 = 0.f;
#pragma unroll
  for (int s = 0; s < 3; ++s) {
    size_t off = (size_t)s * Mtot;
    v00 += part[(off + m00) * NCOMB + ch];
    v01 += part[(off + m01) * NCOMB + ch];
    v10 += part[(off + m10) * NCOMB + ch];
    v11 += part[(off + m11) * NCOMB + ch];
  }
  return v00 * (1.f - fx) * (1.f - fy) + v01 * fx * (1.f - fy) +
         v10 * (1.f - fx) * fy + v11 * fx * fy;
}

// ----------------------------------------------- K4a: per-pixel decode + sem pts
// sem_ws layout: [pt][Mtot] float2
__global__ __launch_bounds__(256) void decode(
    const float* __restrict__ part, const float* __restrict__ part_lo,
    const float* __restrict__ dyn_b, const float* __restrict__ anchor,
    float* __restrict__ out_coarse, float* __restrict__ out_regbox,
    float2* __restrict__ sem_ws, int Mtot, int MtotLo, int H, int W, int P,
    int level) {
  int p = blockIdx.x * 256 + threadIdx.x;
  int n = blockIdx.y;
  if (p >= P) return;
  int m = n * P + p;
  float pr[38];
  {
    const float* p0 = part + (size_t)m * NCOMB;
    const float* p1 = part + ((size_t)Mtot + m) * NCOMB;
    const float* p2 = part + ((size_t)2 * Mtot + m) * NCOMB;
#pragma unroll
    for (int o = 0; o < 38; ++o) pr[o] = p0[o] + p1[o] + p2[o];
#pragma unroll
    for (int o = 0; o < DYN_CH; ++o) pr[o] += dyn_b[o];
  }
  const float* an = anchor + (size_t)n * 4 * P + p;
  float cb[4];
#pragma unroll
  for (int k = 0; k < 4; ++k) cb[k] = an[(size_t)k * P] + pr[k];
  float* oc = out_coarse + (size_t)n * 4 * P + p;
#pragma unroll
  for (int k = 0; k < 4; ++k) oc[(size_t)k * P] = cb[k];

  float thr_y = (cb[3] - cb[1]) * 0.25f;
  float thr_x = (cb[2] - cb[0]) * 0.25f;
  float bo[4];
#pragma unroll
  for (int j = 0; j < 4; ++j) {
    float thr = (j & 1) ? thr_x : thr_y;
    float b = pr[4 + j];
    float extra = fmaxf(b - thr, 0.f) + fminf(b + thr, 0.f);
    bo[j] = b - extra;
  }
  float cx = 0.5f * (cb[0] + cb[2]);
  float cy = 0.5f * (cb[1] + cb[3]);
  float bp[8] = {cb[0], cy + bo[0], cx + bo[1], cb[1],
                 cb[2], cy + bo[2], cx + bo[3], cb[3]};

  int nbase = n * P;
  int nbaseLo = n * (100 * 152);
  float rb[4];
#pragma unroll
  for (int pt = 0; pt < 4; ++pt) {
    float hi = samp48(part, Mtot, nbase, W, H, bp[2 * pt], bp[2 * pt + 1],
                      DYN_CH + pt);
    float val;
    if (level == 0) {
      val = hi;
    } else {
      float lo = 0.5f * samp48(part_lo, MtotLo, nbaseLo, 152, 100,
                               bp[2 * pt] * 2.f, bp[2 * pt + 1] * 2.f,
                               DYN_CH + pt);
      float e0 = pr[26 + 2 * pt], e1 = pr[26 + 2 * pt + 1];
      float mx = fmaxf(e0, e1);
      float w0 = expf(e0 - mx), w1 = expf(e1 - mx);
      val = (lo * w0 + hi * w1) / (w0 + w1);
    }
    rb[pt] = val;
  }
  float* orb = out_regbox + (size_t)n * 4 * P + p;
  orb[0] = bp[0] + rb[0];
  orb[(size_t)P] = bp[3] + rb[1];
  orb[(size_t)2 * P] = bp[4] + rb[2];
  orb[(size_t)3 * P] = bp[7] + rb[3];

  float sx[9] = {cb[0], cb[0], cb[0], cx, cx, cx, cb[2], cb[2], cb[2]};
  float sy[9] = {cb[1], cy, cb[3], cb[1], cy, cb[3], cb[1], cy, cb[3]};
#pragma unroll
  for (int k = 0; k < 9; ++k) {
    float2 s = {sx[k] + pr[8 + 2 * k], sy[k] + pr[8 + 2 * k + 1]};
    sem_ws[(size_t)k * Mtot + m] = s;
  }
}

// ------------- K4b: cls gather, channel-major map: thread = (pixel, class)
// wave = 64 consecutive pixels x 1 class -> coalesced taps & writes
__global__ __launch_bounds__(256) void cls_gather_t(
    const __hip_bfloat16* __restrict__ mapT, const float2* __restrict__ sem_ws,
    const float* __restrict__ bias, float* __restrict__ out, int Mtot, int H,
    int W, int P) {
  int lane = threadIdx.x & 63;
  int cls = blockIdx.y * 4 + (threadIdx.x >> 6);
  int m = blockIdx.x * 64 + lane;
  if (m >= Mtot) return;
  int n = m / P;
  int p = m - n * P;
  int nbase = n * P;
  float acc = 0.f;
#pragma unroll
  for (int pt = 0; pt < 9; ++pt) {
    float2 s = sem_ws[(size_t)pt * Mtot + m];
    float xc = fminf(fmaxf(s.x, 0.f), (float)(W - 1));
    float yc = fminf(fmaxf(s.y, 0.f), (float)(H - 1));
    float x0f = floorf(xc), y0f = floorf(yc);
    float fx = xc - x0f, fy = yc - y0f;
    int x0 = (int)x0f, y0 = (int)y0f;
    int x1 = min(x0 + 1, W - 1), y1 = min(y0 + 1, H - 1);
    const __hip_bfloat16* plane =
        mapT + (size_t)(pt * NUM_CLASSES + cls) * Mtot + nbase;
    float v00 = __bfloat162float(plane[y0 * W + x0]);
    float v01 = __bfloat162float(plane[y0 * W + x1]);
    float v10 = __bfloat162float(plane[y1 * W + x0]);
    float v11 = __bfloat162float(plane[y1 * W + x1]);
    acc += (v00 * (1.f - fx) + v01 * fx) * (1.f - fy) +
           (v10 * (1.f - fx) + v11 * fx) * fy;
  }
  out[((size_t)n * NUM_CLASSES + cls) * P + p] = acc + bias[cls];
}

// ---------------------------------------------------------------------- launch
extern "C" void kernel_launch(void* const* d_in, const int* in_sizes, int n_in,
                              void* d_out, int out_size, void* d_ws,
                              size_t ws_size, hipStream_t stream) {
  const float* reg_feat0 = (const float*)d_in[0];
  const float* reg_feat1 = (const float*)d_in[1];
  const float* cls_feat0 = (const float*)d_in[2];
  const float* cls_feat1 = (const float*)d_in[3];
  const float* anchor0 = (const float*)d_in[4];
  const float* anchor1 = (const float*)d_in[5];
  const float* dyn_w = (const float*)d_in[6];
  const float* dyn_b = (const float*)d_in[7];
  const float* reg_w = (const float*)d_in[8];
  const float* cls_w = (const float*)d_in[9];
  const float* cls_b = (const float*)d_in[10];

  const int P0 = 15200, P1 = 3800;
  const int M0 = N_BATCH * P0;          // 30400
  const int M1 = N_BATCH * P1;          // 7600
  const int MT0 = (M0 + 255) / 256;     // 119
  const int MT1 = (M1 + 255) / 256;     // 30
  const int CT0 = (M0 + 63) / 64;       // 475
  const int CT1 = (M1 + 63) / 64;       // 119

  float* out = (float*)d_out;
  float* out_cls0 = out;
  float* out_cls1 = out_cls0 + (size_t)N_BATCH * NUM_CLASSES * P0;
  float* out_coarse0 = out_cls1 + (size_t)N_BATCH * NUM_CLASSES * P1;
  float* out_coarse1 = out_coarse0 + (size_t)N_BATCH * 4 * P0;
  float* out_reg0 = out_coarse1 + (size_t)N_BATCH * 4 * P1;
  float* out_reg1 = out_reg0 + (size_t)N_BATCH * 4 * P0;

  // ---- workspace layout (bytes)
  char* w = (char*)d_ws;
  float2* semb = (float2*)w;                       w += 2188800;   // 9*M0*8
  __hip_bfloat16* bpack = (__hip_bfloat16*)w;      w += 368640;
  __hip_bfloat16* wpack = (__hip_bfloat16*)w;      w += 221184;
  __hip_bfloat16* apack = (__hip_bfloat16*)w;      w += 15564800;
  __hip_bfloat16* rpack = (__hip_bfloat16*)w;      w += 15564800;
  float* part0 = (float*)w;                        w += 17510400;  // 3*30400*48 f
  float* part1 = (float*)(((char*)rpack) + 4194304);  // alias tail of rpack (L1)
  __hip_bfloat16* clsmapT = (__hip_bfloat16*)w;    w += 43776256;  // [720][M] + pad

  hipLaunchKernelGGL(pack_b, dim3(90), dim3(256), 0, stream, cls_w, bpack);
  hipLaunchKernelGGL(pack_w, dim3(54), dim3(256), 0, stream, dyn_w, reg_w, wpack);

  // ---- level 0
  hipLaunchKernelGGL(pack_a, dim3(MT0 * 32), dim3(256), 0, stream, cls_feat0,
                     apack, P0, M0);
  hipLaunchKernelGGL(cls_gemm_mfma, dim3(MT0, 9), dim3(256), 0, stream,
                     (const uint4*)apack, (const uint4*)bpack, clsmapT, M0);
  hipLaunchKernelGGL(pack_row, dim3(MT0 * 32), dim3(256), 0, stream, reg_feat0,
                     rpack, P0, M0);
  hipLaunchKernelGGL(dyn_reg_conv_mfma, dim3(CT0, 3), dim3(256), 0, stream,
                     (const uint4*)rpack, (const uint4*)wpack, part0, M0, P0,
                     152, 100);
  hipLaunchKernelGGL(decode, dim3((P0 + 255) / 256, N_BATCH), dim3(256), 0,
                     stream, part0, part0, dyn_b, anchor0, out_coarse0, out_reg0,
                     semb, M0, M0, 100, 152, P0, 0);
  hipLaunchKernelGGL(cls_gather_t, dim3(CT0, 20), dim3(256), 0, stream, clsmapT,
                     semb, cls_b, out_cls0, M0, 100, 152, P0);

  // ---- level 1
  hipLaunchKernelGGL(pack_a, dim3(MT1 * 32), dim3(256), 0, stream, cls_feat1,
                     apack, P1, M1);
  hipLaunchKernelGGL(cls_gemm_mfma, dim3(MT1, 9), dim3(256), 0, stream,
                     (const uint4*)apack, (const uint4*)bpack, clsmapT, M1);
  hipLaunchKernelGGL(pack_row, dim3(MT1 * 32), dim3(256), 0, stream, reg_feat1,
                     rpack, P1, M1);
  hipLaunchKernelGGL(dyn_reg_conv_mfma, dim3(CT1, 3), dim3(256), 0, stream,
                     (const uint4*)rpack, (const uint4*)wpack, part1, M1, P1,
                     76, 50);
  hipLaunchKernelGGL(decode, dim3((P1 + 255) / 256, N_BATCH), dim3(256), 0,
                     stream, part1, part0, dyn_b, anchor1, out_coarse1, out_reg1,
                     semb, M1, M0, 50, 76, P1, 1);
  hipLaunchKernelGGL(cls_gather_t, dim3(CT1, 20), dim3(256), 0, stream, clsmapT,
                     semb, cls_b, out_cls1, M1, 50, 76, P1);
}

// Round 5
// 332.878 us; speedup vs baseline: 1.1480x; 1.1480x over previous
//
#include <hip/hip_runtime.h>
#include <hip/hip_bf16.h>
#include <cstdint>

#define N_BATCH 2
#define C_IN 256
#define DYN_CH 34
#define CLS_CH 720
#define NUM_CLASSES 80
#define NCOMB 48

#define P0c 15200
#define P1c 3800
#define M0c 30400
#define M1c 7600
#define MT0c 119
#define MT1c 30
#define CT0c 475
#define CT1c 119

typedef __attribute__((ext_vector_type(8))) short short8;   // 8 bf16
typedef __attribute__((ext_vector_type(4))) float f32x4;

typedef const unsigned int __attribute__((address_space(1)))* gas1_t;
typedef unsigned int __attribute__((address_space(3)))* las3_t;

__device__ __forceinline__ void async_ld16(const void* g, void* l) {
  __builtin_amdgcn_global_load_lds((gas1_t)g, (las3_t)l, 16, 0, 0);
}

// ---------------- pack_misc: cls W (blocks 0..89) + dyn/reg W (blocks 90..143)
__global__ __launch_bounds__(256) void pack_misc(
    const float* __restrict__ cls_w, const float* __restrict__ dyn_w,
    const float* __restrict__ reg_w, __hip_bfloat16* __restrict__ bpack,
    __hip_bfloat16* __restrict__ wpack) {
  int b = blockIdx.x;
  if (b < 90) {
    int u = b * 256 + threadIdx.x;
    if (u >= 9 * 32 * 80) return;
    int ntile = u / 2560;
    int rem = u % 2560;
    int kcg = rem / 80;
    int ochl = rem % 80;
    int och = ntile * 80 + ochl;
    const float* wr = cls_w + (size_t)och * C_IN + kcg * 8;
    __hip_bfloat16 tmp[8];
#pragma unroll
    for (int c = 0; c < 8; ++c) tmp[c] = __float2bfloat16(wr[c]);
    *(uint4*)(bpack + (size_t)u * 8) = *(const uint4*)tmp;
  } else {
    int u = (b - 90) * 256 + threadIdx.x;  // 13824 units
    if (u >= 13824) return;
    int j = u / 768;
    int r = u % 768;
    int n = r / 16;
    int s = r % 16;
    int ku = j * 16 + (s ^ (n & 7));
    int k0 = ku * 8;
    int tap = k0 >> 8;
    int c0 = k0 & 255;
    __hip_bfloat16 tmp[8];
#pragma unroll
    for (int i = 0; i < 8; ++i) {
      int c = c0 + i;
      float v = 0.f;
      if (n < DYN_CH) v = dyn_w[((size_t)n * C_IN + c) * 9 + tap];
      else if (n < DYN_CH + 4 && tap == 4) v = reg_w[(size_t)(n - DYN_CH) * C_IN + c];
      tmp[i] = __float2bfloat16(v);
    }
    *(uint4*)(wpack + (size_t)u * 8) = *(const uint4*)tmp;
  }
}

// ---------------- pack_feat: 4 jobs in one launch
// j0: cls0 -> apack0 (tiled)   blocks [0, 3808)
// j1: cls1 -> apack1 (tiled)   blocks [3808, 4768)
// j2: reg0 -> rpack0 (rowmaj)  blocks [4768, 8576)
// j3: reg1 -> rpack1 (rowmaj)  blocks [8576, 9536)
__global__ __launch_bounds__(256) void pack_feat(
    const float* __restrict__ cls0, const float* __restrict__ cls1,
    const float* __restrict__ reg0, const float* __restrict__ reg1,
    __hip_bfloat16* __restrict__ a0, __hip_bfloat16* __restrict__ a1,
    __hip_bfloat16* __restrict__ r0, __hip_bfloat16* __restrict__ r1) {
  int b = blockIdx.x;
  const float* src;
  __hip_bfloat16* dst;
  int P, Mtot;
  bool tiled;
  if (b < 3808)      { src = cls0; dst = a0; P = P0c; Mtot = M0c; tiled = true;  }
  else if (b < 4768) { b -= 3808; src = cls1; dst = a1; P = P1c; Mtot = M1c; tiled = true; }
  else if (b < 8576) { b -= 4768; src = reg0; dst = r0; P = P0c; Mtot = M0c; tiled = false; }
  else               { b -= 8576; src = reg1; dst = r1; P = P1c; Mtot = M1c; tiled = false; }
  size_t u = (size_t)b * 256 + threadIdx.x;
  int mtile = (int)(u >> 13);
  int rem = (int)(u & 8191);
  int kcg = rem >> 8;
  int row = rem & 255;
  int m = mtile * 256 + row;
  __hip_bfloat16 tmp[8];
  if (m < Mtot) {
    int n = m / P, p = m - n * P;
    const float* xb = src + (size_t)n * C_IN * P + (size_t)(kcg * 8) * P + p;
#pragma unroll
    for (int c = 0; c < 8; ++c) tmp[c] = __float2bfloat16(xb[(size_t)c * P]);
  } else {
    if (!tiled) return;  // row-major: skip OOB
#pragma unroll
    for (int c = 0; c < 8; ++c) tmp[c] = __float2bfloat16(0.f);
  }
  if (tiled)
    *(uint4*)(dst + u * 8) = *(const uint4*)tmp;
  else
    *((uint4*)dst + (size_t)m * 32 + kcg) = *(const uint4*)tmp;
}

// ------------------- cls 1x1 bf16 MFMA GEMM -> bf16 map pixel-major [m][720]
// both levels fused: mtile < 119 -> L0, else L1
__global__ __launch_bounds__(256) void cls_gemm_mfma(
    const uint4* __restrict__ Ap0, const uint4* __restrict__ Ap1,
    const uint4* __restrict__ Bp, __hip_bfloat16* __restrict__ out0,
    __hip_bfloat16* __restrict__ out1) {
  __shared__ uint4 Ash[1024];
  __shared__ uint4 Bsh[320];
  int tid = threadIdx.x;
  int wave = tid >> 6;
  int lane = tid & 63;
  int l15 = lane & 15;
  int kq = lane >> 4;
  int mtile = blockIdx.x;
  int ntile = blockIdx.y;

  const uint4* Ap;
  __hip_bfloat16* out;
  int Mtot;
  if (mtile < MT0c) { Ap = Ap0; out = out0; Mtot = M0c; }
  else              { mtile -= MT0c; Ap = Ap1; out = out1; Mtot = M1c; }

  const uint4* Ab = Ap + (size_t)mtile * 8192;
  const uint4* Bb = Bp + (size_t)ntile * 2560;

  f32x4 acc[4][5];
#pragma unroll
  for (int i = 0; i < 4; ++i)
#pragma unroll
    for (int j = 0; j < 5; ++j) acc[i][j] = (f32x4)0.f;

  for (int kb = 0; kb < 8; ++kb) {
    const uint4* Aslab = Ab + kb * 1024;
#pragma unroll
    for (int i = 0; i < 4; ++i) {
      int j = wave * 4 + i;
      async_ld16(Aslab + j * 64 + lane, &Ash[j * 64]);
    }
    const uint4* Bslab = Bb + kb * 320;
    for (int j = wave; j < 5; j += 4) {
      async_ld16(Bslab + j * 64 + lane, &Bsh[j * 64]);
    }
    __syncthreads();

    short8 a[4], b[5];
    const uint4* Ar = &Ash[kq * 256 + wave * 64 + l15];
#pragma unroll
    for (int mi = 0; mi < 4; ++mi) a[mi] = *(const short8*)&Ar[mi * 16];
    const uint4* Br = &Bsh[kq * 80 + l15];
#pragma unroll
    for (int ni = 0; ni < 5; ++ni) b[ni] = *(const short8*)&Br[ni * 16];
#pragma unroll
    for (int mi = 0; mi < 4; ++mi)
#pragma unroll
      for (int ni = 0; ni < 5; ++ni)
        acc[mi][ni] = __builtin_amdgcn_mfma_f32_16x16x32_bf16(
            a[mi], b[ni], acc[mi][ni], 0, 0, 0);
    __syncthreads();
  }

  int gbase = mtile * 256 + wave * 64;
#pragma unroll
  for (int mi = 0; mi < 4; ++mi) {
#pragma unroll
    for (int r = 0; r < 4; ++r) {
      int g = gbase + mi * 16 + kq * 4 + r;
      if (g >= Mtot) continue;
      __hip_bfloat16* orow = out + (size_t)g * CLS_CH + ntile * 80 + l15;
#pragma unroll
      for (int ni = 0; ni < 5; ++ni)
        orow[ni * 16] = __float2bfloat16(acc[mi][ni][r]);
    }
  }
}

// ---------- dyn3x3 + reg1x1 fused implicit-GEMM MFMA, split-K=3, both levels
__global__ __launch_bounds__(256) void dyn_reg_conv_mfma(
    const uint4* __restrict__ rp0, const uint4* __restrict__ rp1,
    const uint4* __restrict__ wp, float* __restrict__ part0,
    float* __restrict__ part1) {
  __shared__ uint4 Bs[768];
  int tid = threadIdx.x;
  int wave = tid >> 6;
  int lane = tid & 63;
  int l15 = lane & 15;
  int kq = lane >> 4;
  int seg = blockIdx.y;
  int bx = blockIdx.x;

  const uint4* rp;
  float* part;
  int Mtot, P, W, H;
  if (bx < CT0c) { rp = rp0; part = part0; Mtot = M0c; P = P0c; W = 152; H = 100; }
  else { bx -= CT0c; rp = rp1; part = part1; Mtot = M1c; P = P1c; W = 76; H = 50; }

  int m = bx * 64 + wave * 16 + l15;
  bool mval = (m < Mtot);
  int mc = mval ? m : 0;
  int n = mc / P;
  int rem = mc - n * P;
  int y = rem / W;
  int x = rem - y * W;

  f32x4 acc[3];
#pragma unroll
  for (int i = 0; i < 3; ++i) acc[i] = (f32x4)0.f;

  for (int jj = 0; jj < 6; ++jj) {
    int j = seg * 6 + jj;
    const uint4* wsrc = wp + (size_t)j * 768 + wave * 192;
#pragma unroll
    for (int i = 0; i < 3; ++i)
      async_ld16(wsrc + i * 64 + lane, &Bs[wave * 192 + i * 64]);

    int tap = j >> 1;
    int cb8 = (j & 1) * 16;
    int dy = tap / 3 - 1, dx = tap % 3 - 1;
    int sy = y + dy, sx = x + dx;
    bool val = mval && ((unsigned)sy < (unsigned)H) && ((unsigned)sx < (unsigned)W);
    size_t srow = (size_t)(m + dy * W + dx);
    uint4 a[4];
#pragma unroll
    for (int t = 0; t < 4; ++t) {
      uint4 v = {0u, 0u, 0u, 0u};
      if (val) v = rp[srow * 32 + cb8 + t * 4 + kq];
      a[t] = v;
    }
    __syncthreads();
#pragma unroll
    for (int t = 0; t < 4; ++t) {
#pragma unroll
      for (int ni = 0; ni < 3; ++ni) {
        int nn = ni * 16 + l15;
        short8 bf = *(const short8*)&Bs[nn * 16 + ((t * 4 + kq) ^ (nn & 7))];
        acc[ni] = __builtin_amdgcn_mfma_f32_16x16x32_bf16(
            *(short8*)&a[t], bf, acc[ni], 0, 0, 0);
      }
    }
    __syncthreads();
  }

  int mrow = bx * 64 + wave * 16 + kq * 4;
#pragma unroll
  for (int r = 0; r < 4; ++r) {
    int mm = mrow + r;
    if (mm >= Mtot) continue;
    float* dst = part + ((size_t)seg * Mtot + mm) * NCOMB + l15;
#pragma unroll
    for (int ni = 0; ni < 3; ++ni) dst[ni * 16] = acc[ni][r];
  }
}

// -------------------- bilinear sample of combined-map channel (3 K-segments)
__device__ __forceinline__ float samp48(const float* __restrict__ part,
                                        int Mtot, int nbase, int W, int H,
                                        float px, float py, int ch) {
  float xc = fminf(fmaxf(px, 0.f), (float)(W - 1));
  float yc = fminf(fmaxf(py, 0.f), (float)(H - 1));
  float x0f = floorf(xc), y0f = floorf(yc);
  float fx = xc - x0f, fy = yc - y0f;
  int x0 = (int)x0f, y0 = (int)y0f;
  int x1 = min(x0 + 1, W - 1), y1 = min(y0 + 1, H - 1);
  size_t m00 = (size_t)(nbase + y0 * W + x0);
  size_t m01 = (size_t)(nbase + y0 * W + x1);
  size_t m10 = (size_t)(nbase + y1 * W + x0);
  size_t m11 = (size_t)(nbase + y1 * W + x1);
  float v00 = 0.f, v01 = 0.f, v10 = 0.f, v11 = 0.f;
#pragma unroll
  for (int s = 0; s < 3; ++s) {
    size_t off = (size_t)s * Mtot;
    v00 += part[(off + m00) * NCOMB + ch];
    v01 += part[(off + m01) * NCOMB + ch];
    v10 += part[(off + m10) * NCOMB + ch];
    v11 += part[(off + m11) * NCOMB + ch];
  }
  return v00 * (1.f - fx) * (1.f - fy) + v01 * fx * (1.f - fy) +
         v10 * (1.f - fx) * fy + v11 * fx * fy;
}

// ---------------- decode, both levels fused (x<60 -> L0, else L1)
// sem layout: [pt][Mtot] float2
__global__ __launch_bounds__(256) void decode(
    const float* __restrict__ part0, const float* __restrict__ part1,
    const float* __restrict__ dyn_b, const float* __restrict__ anchor0,
    const float* __restrict__ anchor1, float* __restrict__ out_coarse0,
    float* __restrict__ out_coarse1, float* __restrict__ out_regbox0,
    float* __restrict__ out_regbox1, float2* __restrict__ sem0,
    float2* __restrict__ sem1) {
  int bx = blockIdx.x;
  int n = blockIdx.y;
  const float* part;
  const float* anchor;
  float* out_coarse;
  float* out_regbox;
  float2* sem_ws;
  int Mtot, H, W, P, level;
  if (bx < 60) {
    part = part0; anchor = anchor0; out_coarse = out_coarse0;
    out_regbox = out_regbox0; sem_ws = sem0;
    Mtot = M0c; H = 100; W = 152; P = P0c; level = 0;
  } else {
    bx -= 60;
    part = part1; anchor = anchor1; out_coarse = out_coarse1;
    out_regbox = out_regbox1; sem_ws = sem1;
    Mtot = M1c; H = 50; W = 76; P = P1c; level = 1;
  }
  int p = bx * 256 + threadIdx.x;
  if (p >= P) return;
  int m = n * P + p;
  float pr[38];
  {
    const float* q0 = part + (size_t)m * NCOMB;
    const float* q1 = part + ((size_t)Mtot + m) * NCOMB;
    const float* q2 = part + ((size_t)2 * Mtot + m) * NCOMB;
#pragma unroll
    for (int o = 0; o < 38; ++o) pr[o] = q0[o] + q1[o] + q2[o];
#pragma unroll
    for (int o = 0; o < DYN_CH; ++o) pr[o] += dyn_b[o];
  }
  const float* an = anchor + (size_t)n * 4 * P + p;
  float cb[4];
#pragma unroll
  for (int k = 0; k < 4; ++k) cb[k] = an[(size_t)k * P] + pr[k];
  float* oc = out_coarse + (size_t)n * 4 * P + p;
#pragma unroll
  for (int k = 0; k < 4; ++k) oc[(size_t)k * P] = cb[k];

  float thr_y = (cb[3] - cb[1]) * 0.25f;
  float thr_x = (cb[2] - cb[0]) * 0.25f;
  float bo[4];
#pragma unroll
  for (int j = 0; j < 4; ++j) {
    float thr = (j & 1) ? thr_x : thr_y;
    float b = pr[4 + j];
    float extra = fmaxf(b - thr, 0.f) + fminf(b + thr, 0.f);
    bo[j] = b - extra;
  }
  float cx = 0.5f * (cb[0] + cb[2]);
  float cy = 0.5f * (cb[1] + cb[3]);
  float bp[8] = {cb[0], cy + bo[0], cx + bo[1], cb[1],
                 cb[2], cy + bo[2], cx + bo[3], cb[3]};

  int nbase = n * P;
  int nbaseLo = n * P0c;
  float rb[4];
#pragma unroll
  for (int pt = 0; pt < 4; ++pt) {
    float hi = samp48(part, Mtot, nbase, W, H, bp[2 * pt], bp[2 * pt + 1],
                      DYN_CH + pt);
    float val;
    if (level == 0) {
      val = hi;
    } else {
      float lo = 0.5f * samp48(part0, M0c, nbaseLo, 152, 100, bp[2 * pt] * 2.f,
                               bp[2 * pt + 1] * 2.f, DYN_CH + pt);
      float e0 = pr[26 + 2 * pt], e1 = pr[26 + 2 * pt + 1];
      float mx = fmaxf(e0, e1);
      float w0 = expf(e0 - mx), w1 = expf(e1 - mx);
      val = (lo * w0 + hi * w1) / (w0 + w1);
    }
    rb[pt] = val;
  }
  float* orb = out_regbox + (size_t)n * 4 * P + p;
  orb[0] = bp[0] + rb[0];
  orb[(size_t)P] = bp[3] + rb[1];
  orb[(size_t)2 * P] = bp[4] + rb[2];
  orb[(size_t)3 * P] = bp[7] + rb[3];

  float sx[9] = {cb[0], cb[0], cb[0], cx, cx, cx, cb[2], cb[2], cb[2]};
  float sy[9] = {cb[1], cy, cb[3], cb[1], cy, cb[3], cb[1], cy, cb[3]};
#pragma unroll
  for (int k = 0; k < 9; ++k) {
    float2 s = {sx[k] + pr[8 + 2 * k], sy[k] + pr[8 + 2 * k + 1]};
    sem_ws[(size_t)k * Mtot + m] = s;
  }
}

// ------------- gather: pixel-major map, wave = 1 px, lane = cls (+16 tail)
// both levels fused; all 9 points' idx/weights hoisted before tap loads
__global__ __launch_bounds__(256) void cls_gather_f(
    const __hip_bfloat16* __restrict__ map0,
    const __hip_bfloat16* __restrict__ map1, const float2* __restrict__ sem0,
    const float2* __restrict__ sem1, const float* __restrict__ bias,
    float* __restrict__ outc0, float* __restrict__ outc1) {
  int b = blockIdx.x;
  const __hip_bfloat16* map;
  const float2* sem;
  float* out;
  int Mtot, P, W, H;
  if (b < 7600) { map = map0; sem = sem0; out = outc0; Mtot = M0c; P = P0c; W = 152; H = 100; }
  else { b -= 7600; map = map1; sem = sem1; out = outc1; Mtot = M1c; P = P1c; W = 76; H = 50; }
  int lane = threadIdx.x & 63;
  int m = b * 4 + (threadIdx.x >> 6);
  if (m >= Mtot) return;
  int n = m / P;
  int p = m - n * P;
  int nbase = n * P;

  // hoisted per-point data
  int base[9], dX[9], dYW[9];
  float w00[9], w01[9], w10[9], w11[9];
#pragma unroll
  for (int pt = 0; pt < 9; ++pt) {
    float2 s = sem[(size_t)pt * Mtot + m];
    float xc = fminf(fmaxf(s.x, 0.f), (float)(W - 1));
    float yc = fminf(fmaxf(s.y, 0.f), (float)(H - 1));
    float x0f = floorf(xc), y0f = floorf(yc);
    float fx = xc - x0f, fy = yc - y0f;
    int x0 = (int)x0f, y0 = (int)y0f;
    int x1 = min(x0 + 1, W - 1), y1 = min(y0 + 1, H - 1);
    base[pt] = nbase + y0 * W + x0;
    dX[pt] = x1 - x0;
    dYW[pt] = (y1 - y0) * W;
    w00[pt] = (1.f - fx) * (1.f - fy);
    w01[pt] = fx * (1.f - fy);
    w10[pt] = (1.f - fx) * fy;
    w11[pt] = fx * fy;
  }
  float acc0 = 0.f, acc1 = 0.f;
#pragma unroll
  for (int pt = 0; pt < 9; ++pt) {
    const __hip_bfloat16* pl = map + (size_t)base[pt] * CLS_CH + pt * 80 + lane;
    size_t o01 = (size_t)dX[pt] * CLS_CH;
    size_t o10 = (size_t)dYW[pt] * CLS_CH;
    float v00 = __bfloat162float(pl[0]);
    float v01 = __bfloat162float(pl[o01]);
    float v10 = __bfloat162float(pl[o10]);
    float v11 = __bfloat162float(pl[o10 + o01]);
    acc0 += w00[pt] * v00 + w01[pt] * v01 + w10[pt] * v10 + w11[pt] * v11;
    if (lane < 16) {
      float u00 = __bfloat162float(pl[64]);
      float u01 = __bfloat162float(pl[o01 + 64]);
      float u10 = __bfloat162float(pl[o10 + 64]);
      float u11 = __bfloat162float(pl[o10 + o01 + 64]);
      acc1 += w00[pt] * u00 + w01[pt] * u01 + w10[pt] * u10 + w11[pt] * u11;
    }
  }
  float* on = out + (size_t)n * NUM_CLASSES * P + p;
  on[(size_t)lane * P] = acc0 + bias[lane];
  if (lane < 16) on[(size_t)(lane + 64) * P] = acc1 + bias[lane + 64];
}

// ---------------------------------------------------------------------- launch
extern "C" void kernel_launch(void* const* d_in, const int* in_sizes, int n_in,
                              void* d_out, int out_size, void* d_ws,
                              size_t ws_size, hipStream_t stream) {
  const float* reg_feat0 = (const float*)d_in[0];
  const float* reg_feat1 = (const float*)d_in[1];
  const float* cls_feat0 = (const float*)d_in[2];
  const float* cls_feat1 = (const float*)d_in[3];
  const float* anchor0 = (const float*)d_in[4];
  const float* anchor1 = (const float*)d_in[5];
  const float* dyn_w = (const float*)d_in[6];
  const float* dyn_b = (const float*)d_in[7];
  const float* reg_w = (const float*)d_in[8];
  const float* cls_w = (const float*)d_in[9];
  const float* cls_b = (const float*)d_in[10];

  float* out = (float*)d_out;
  float* out_cls0 = out;
  float* out_cls1 = out_cls0 + (size_t)N_BATCH * NUM_CLASSES * P0c;
  float* out_coarse0 = out_cls1 + (size_t)N_BATCH * NUM_CLASSES * P1c;
  float* out_coarse1 = out_coarse0 + (size_t)N_BATCH * 4 * P0c;
  float* out_reg0 = out_coarse1 + (size_t)N_BATCH * 4 * P1c;
  float* out_reg1 = out_reg0 + (size_t)N_BATCH * 4 * P0c;

  // ---- workspace layout (bytes)
  char* w = (char*)d_ws;
  __hip_bfloat16* bpack = (__hip_bfloat16*)w;   w += 368640;
  __hip_bfloat16* wpack = (__hip_bfloat16*)w;   w += 221184;
  float2* sem0 = (float2*)w;                    w += 2188800;   // 9*M0*8
  float2* sem1 = (float2*)w;                    w += 547200;    // 9*M1*8
  char* apack_base = w;
  __hip_bfloat16* apack0 = (__hip_bfloat16*)w;  w += 15597568;  // 119*8192*16
  __hip_bfloat16* apack1 = (__hip_bfloat16*)w;  w += 3932160;   // 30*8192*16
  __hip_bfloat16* rpack0 = (__hip_bfloat16*)w;  w += 15564800;  // M0*512
  __hip_bfloat16* rpack1 = (__hip_bfloat16*)w;  w += 3891200;   // M1*512
  float* part1 = (float*)w;                     w += 4377600;   // 3*M1*48*4
  __hip_bfloat16* map0 = (__hip_bfloat16*)w;    w += 43776000;  // M0*720*2
  __hip_bfloat16* map1 = (__hip_bfloat16*)w;    w += 10944000;  // M1*720*2
  // part0 (3*M0*48*4 = 17510400 B) aliases apack0+apack1 (19529728 B),
  // which are dead after the gemm launch (stream-ordered).
  float* part0 = (float*)apack_base;

  hipLaunchKernelGGL(pack_misc, dim3(144), dim3(256), 0, stream, cls_w, dyn_w,
                     reg_w, bpack, wpack);
  hipLaunchKernelGGL(pack_feat, dim3(9536), dim3(256), 0, stream, cls_feat0,
                     cls_feat1, reg_feat0, reg_feat1, apack0, apack1, rpack0,
                     rpack1);
  hipLaunchKernelGGL(cls_gemm_mfma, dim3(MT0c + MT1c, 9), dim3(256), 0, stream,
                     (const uint4*)apack0, (const uint4*)apack1,
                     (const uint4*)bpack, map0, map1);
  hipLaunchKernelGGL(dyn_reg_conv_mfma, dim3(CT0c + CT1c, 3), dim3(256), 0,
                     stream, (const uint4*)rpack0, (const uint4*)rpack1,
                     (const uint4*)wpack, part0, part1);
  hipLaunchKernelGGL(decode, dim3(75, N_BATCH), dim3(256), 0, stream, part0,
                     part1, dyn_b, anchor0, anchor1, out_coarse0, out_coarse1,
                     out_reg0, out_reg1, sem0, sem1);
  hipLaunchKernelGGL(cls_gather_f, dim3(7600 + 1900), dim3(256), 0, stream,
                     map0, map1, sem0, sem1, cls_b, out_cls0, out_cls1);
}

// Round 6
// 281.598 us; speedup vs baseline: 1.3570x; 1.1821x over previous
//
#include <hip/hip_runtime.h>
#include <hip/hip_bf16.h>
#include <cstdint>

#define N_BATCH 2
#define C_IN 256
#define DYN_CH 34
#define CLS_CH 720
#define NUM_CLASSES 80
#define NCOMB 48

#define P0c 15200
#define P1c 3800
#define M0c 30400
#define M1c 7600
#define MT0c 119
#define MT1c 30
#define CT0c 475
#define CT1c 119

typedef __attribute__((ext_vector_type(8))) short short8;   // 8 bf16
typedef __attribute__((ext_vector_type(4))) float f32x4;

typedef const unsigned int __attribute__((address_space(1)))* gas1_t;
typedef unsigned int __attribute__((address_space(3)))* las3_t;

__device__ __forceinline__ void async_ld16(const void* g, void* l) {
  __builtin_amdgcn_global_load_lds((gas1_t)g, (las3_t)l, 16, 0, 0);
}

// ---------------- pack_feat: all 4 feature packs (tiled layout) + weight packs
// blocks [0,2384): feature mtile-packs; [2384,2474): cls W; [2474,2528): dyn/reg W
__global__ __launch_bounds__(256) void pack_feat(
    const float* __restrict__ cls0, const float* __restrict__ cls1,
    const float* __restrict__ reg0, const float* __restrict__ reg1,
    const float* __restrict__ cls_w, const float* __restrict__ dyn_w,
    const float* __restrict__ reg_w, __hip_bfloat16* __restrict__ a0,
    __hip_bfloat16* __restrict__ a1, __hip_bfloat16* __restrict__ r0,
    __hip_bfloat16* __restrict__ r1, __hip_bfloat16* __restrict__ bpack,
    __hip_bfloat16* __restrict__ wpack) {
  int b = blockIdx.x;
  if (b >= 2384) {
    b -= 2384;
    if (b < 90) {  // cls weights -> bpack [ntile][kcg][och]
      int u = b * 256 + threadIdx.x;
      if (u >= 9 * 32 * 80) return;
      int ntile = u / 2560;
      int rem = u % 2560;
      int kcg = rem / 80;
      int ochl = rem % 80;
      int och = ntile * 80 + ochl;
      const float* wr = cls_w + (size_t)och * C_IN + kcg * 8;
      __hip_bfloat16 tmp[8];
#pragma unroll
      for (int c = 0; c < 8; ++c) tmp[c] = __float2bfloat16(wr[c]);
      *(uint4*)(bpack + (size_t)u * 8) = *(const uint4*)tmp;
    } else {  // dyn+reg weights -> wpack swizzled [chunk][n][slot]
      int u = (b - 90) * 256 + threadIdx.x;
      if (u >= 13824) return;
      int j = u / 768;
      int r = u % 768;
      int n = r / 16;
      int s = r % 16;
      int ku = j * 16 + (s ^ (n & 7));
      int k0 = ku * 8;
      int tap = k0 >> 8;
      int c0 = k0 & 255;
      __hip_bfloat16 tmp[8];
#pragma unroll
      for (int i = 0; i < 8; ++i) {
        int c = c0 + i;
        float v = 0.f;
        if (n < DYN_CH) v = dyn_w[((size_t)n * C_IN + c) * 9 + tap];
        else if (n < DYN_CH + 4 && tap == 4)
          v = reg_w[(size_t)(n - DYN_CH) * C_IN + c];
        tmp[i] = __float2bfloat16(v);
      }
      *(uint4*)(wpack + (size_t)u * 8) = *(const uint4*)tmp;
    }
    return;
  }
  // feature pack: b = mtg*8 + j ; wave handles kcg = j*4+wave, lane = 4 px
  int j = b & 7;
  int mtg = b >> 3;
  const float* src;
  __hip_bfloat16* dst;
  int P, Mtot, mtile;
  if (mtg < 119)      { src = cls0; dst = a0; P = P0c; Mtot = M0c; mtile = mtg; }
  else if (mtg < 149) { src = cls1; dst = a1; P = P1c; Mtot = M1c; mtile = mtg - 119; }
  else if (mtg < 268) { src = reg0; dst = r0; P = P0c; Mtot = M0c; mtile = mtg - 149; }
  else                { src = reg1; dst = r1; P = P1c; Mtot = M1c; mtile = mtg - 268; }
  int wave = threadIdx.x >> 6;
  int lane = threadIdx.x & 63;
  int kcg = j * 4 + wave;
  int c0 = kcg * 8;
  int m4 = mtile * 256 + lane * 4;
  uint4* du = (uint4*)dst + (size_t)mtile * 8192 + (size_t)kcg * 256 + lane * 4;
  if (m4 < Mtot) {  // P,Mtot div by 4 -> no n-straddle, all-or-nothing tail
    int n = m4 / P;
    int p = m4 - n * P;
    const float* sp = src + ((size_t)n * C_IN + c0) * P + p;
    float4 f[8];
#pragma unroll
    for (int c = 0; c < 8; ++c) f[c] = *(const float4*)(sp + (size_t)c * P);
#pragma unroll
    for (int i = 0; i < 4; ++i) {
      union { uint4 u; __hip_bfloat16 h[8]; } o;
#pragma unroll
      for (int c = 0; c < 8; ++c) {
        float v = (i == 0) ? f[c].x : (i == 1) ? f[c].y : (i == 2) ? f[c].z : f[c].w;
        o.h[c] = __float2bfloat16(v);
      }
      du[i] = o.u;
    }
  } else {
    uint4 z = {0u, 0u, 0u, 0u};
#pragma unroll
    for (int i = 0; i < 4; ++i) du[i] = z;
  }
}

// ------------------- cls 1x1 bf16 MFMA GEMM -> bf16 map pixel-major [m][720]
__global__ __launch_bounds__(256) void cls_gemm_mfma(
    const uint4* __restrict__ Ap0, const uint4* __restrict__ Ap1,
    const uint4* __restrict__ Bp, __hip_bfloat16* __restrict__ out0,
    __hip_bfloat16* __restrict__ out1) {
  __shared__ uint4 Ash[1024];
  __shared__ uint4 Bsh[320];
  int tid = threadIdx.x;
  int wave = tid >> 6;
  int lane = tid & 63;
  int l15 = lane & 15;
  int kq = lane >> 4;
  int mtile = blockIdx.x;
  int ntile = blockIdx.y;

  const uint4* Ap;
  __hip_bfloat16* out;
  int Mtot;
  if (mtile < MT0c) { Ap = Ap0; out = out0; Mtot = M0c; }
  else              { mtile -= MT0c; Ap = Ap1; out = out1; Mtot = M1c; }

  const uint4* Ab = Ap + (size_t)mtile * 8192;
  const uint4* Bb = Bp + (size_t)ntile * 2560;

  f32x4 acc[4][5];
#pragma unroll
  for (int i = 0; i < 4; ++i)
#pragma unroll
    for (int j = 0; j < 5; ++j) acc[i][j] = (f32x4)0.f;

  for (int kb = 0; kb < 8; ++kb) {
    const uint4* Aslab = Ab + kb * 1024;
#pragma unroll
    for (int i = 0; i < 4; ++i) {
      int j = wave * 4 + i;
      async_ld16(Aslab + j * 64 + lane, &Ash[j * 64]);
    }
    const uint4* Bslab = Bb + kb * 320;
    for (int j = wave; j < 5; j += 4) {
      async_ld16(Bslab + j * 64 + lane, &Bsh[j * 64]);
    }
    __syncthreads();

    short8 a[4], b[5];
    const uint4* Ar = &Ash[kq * 256 + wave * 64 + l15];
#pragma unroll
    for (int mi = 0; mi < 4; ++mi) a[mi] = *(const short8*)&Ar[mi * 16];
    const uint4* Br = &Bsh[kq * 80 + l15];
#pragma unroll
    for (int ni = 0; ni < 5; ++ni) b[ni] = *(const short8*)&Br[ni * 16];
#pragma unroll
    for (int mi = 0; mi < 4; ++mi)
#pragma unroll
      for (int ni = 0; ni < 5; ++ni)
        acc[mi][ni] = __builtin_amdgcn_mfma_f32_16x16x32_bf16(
            a[mi], b[ni], acc[mi][ni], 0, 0, 0);
    __syncthreads();
  }

  int gbase = mtile * 256 + wave * 64;
#pragma unroll
  for (int mi = 0; mi < 4; ++mi) {
#pragma unroll
    for (int r = 0; r < 4; ++r) {
      int g = gbase + mi * 16 + kq * 4 + r;
      if (g >= Mtot) continue;
      __hip_bfloat16* orow = out + (size_t)g * CLS_CH + ntile * 80 + l15;
#pragma unroll
      for (int ni = 0; ni < 5; ++ni)
        orow[ni * 16] = __float2bfloat16(acc[mi][ni][r]);
    }
  }
}

// ---------- dyn3x3 + reg1x1 fused implicit-GEMM MFMA, split-K=3, both levels
// rpack now TILED [mtile][kcg][row] (same as apack)
__global__ __launch_bounds__(256) void dyn_reg_conv_mfma(
    const uint4* __restrict__ rp0, const uint4* __restrict__ rp1,
    const uint4* __restrict__ wp, float* __restrict__ part0,
    float* __restrict__ part1) {
  __shared__ uint4 Bs[768];
  int tid = threadIdx.x;
  int wave = tid >> 6;
  int lane = tid & 63;
  int l15 = lane & 15;
  int kq = lane >> 4;
  int seg = blockIdx.y;
  int bx = blockIdx.x;

  const uint4* rp;
  float* part;
  int Mtot, P, W, H;
  if (bx < CT0c) { rp = rp0; part = part0; Mtot = M0c; P = P0c; W = 152; H = 100; }
  else { bx -= CT0c; rp = rp1; part = part1; Mtot = M1c; P = P1c; W = 76; H = 50; }

  int m = bx * 64 + wave * 16 + l15;
  bool mval = (m < Mtot);
  int mc = mval ? m : 0;
  int n = mc / P;
  int rem = mc - n * P;
  int y = rem / W;
  int x = rem - y * W;

  f32x4 acc[3];
#pragma unroll
  for (int i = 0; i < 3; ++i) acc[i] = (f32x4)0.f;

  for (int jj = 0; jj < 6; ++jj) {
    int j = seg * 6 + jj;
    const uint4* wsrc = wp + (size_t)j * 768 + wave * 192;
#pragma unroll
    for (int i = 0; i < 3; ++i)
      async_ld16(wsrc + i * 64 + lane, &Bs[wave * 192 + i * 64]);

    int tap = j >> 1;
    int cb8 = (j & 1) * 16;
    int dy = tap / 3 - 1, dx = tap % 3 - 1;
    int sy = y + dy, sx = x + dx;
    bool val = mval && ((unsigned)sy < (unsigned)H) && ((unsigned)sx < (unsigned)W);
    int sm = m + dy * W + dx;  // valid pixel index when val
    int smc = val ? sm : 0;
    size_t tbase = (size_t)(smc >> 8) * 8192 + (smc & 255);
    uint4 a[4];
#pragma unroll
    for (int t = 0; t < 4; ++t) {
      uint4 v = {0u, 0u, 0u, 0u};
      if (val) v = rp[tbase + (size_t)(cb8 + t * 4 + kq) * 256];
      a[t] = v;
    }
    __syncthreads();
#pragma unroll
    for (int t = 0; t < 4; ++t) {
#pragma unroll
      for (int ni = 0; ni < 3; ++ni) {
        int nn = ni * 16 + l15;
        short8 bf = *(const short8*)&Bs[nn * 16 + ((t * 4 + kq) ^ (nn & 7))];
        acc[ni] = __builtin_amdgcn_mfma_f32_16x16x32_bf16(
            *(short8*)&a[t], bf, acc[ni], 0, 0, 0);
      }
    }
    __syncthreads();
  }

  int mrow = bx * 64 + wave * 16 + kq * 4;
#pragma unroll
  for (int r = 0; r < 4; ++r) {
    int mm = mrow + r;
    if (mm >= Mtot) continue;
    float* dst = part + ((size_t)seg * Mtot + mm) * NCOMB + l15;
#pragma unroll
    for (int ni = 0; ni < 3; ++ni) dst[ni * 16] = acc[ni][r];
  }
}

// -------------------- bilinear sample of combined-map channel (3 K-segments)
__device__ __forceinline__ float samp48(const float* __restrict__ part,
                                        int Mtot, int nbase, int W, int H,
                                        float px, float py, int ch) {
  float xc = fminf(fmaxf(px, 0.f), (float)(W - 1));
  float yc = fminf(fmaxf(py, 0.f), (float)(H - 1));
  float x0f = floorf(xc), y0f = floorf(yc);
  float fx = xc - x0f, fy = yc - y0f;
  int x0 = (int)x0f, y0 = (int)y0f;
  int x1 = min(x0 + 1, W - 1), y1 = min(y0 + 1, H - 1);
  size_t m00 = (size_t)(nbase + y0 * W + x0);
  size_t m01 = (size_t)(nbase + y0 * W + x1);
  size_t m10 = (size_t)(nbase + y1 * W + x0);
  size_t m11 = (size_t)(nbase + y1 * W + x1);
  float v00 = 0.f, v01 = 0.f, v10 = 0.f, v11 = 0.f;
#pragma unroll
  for (int s = 0; s < 3; ++s) {
    size_t off = (size_t)s * Mtot;
    v00 += part[(off + m00) * NCOMB + ch];
    v01 += part[(off + m01) * NCOMB + ch];
    v10 += part[(off + m10) * NCOMB + ch];
    v11 += part[(off + m11) * NCOMB + ch];
  }
  return v00 * (1.f - fx) * (1.f - fy) + v01 * fx * (1.f - fy) +
         v10 * (1.f - fx) * fy + v11 * fx * fy;
}

// ---------------- decode, both levels fused (bx<60 -> L0, else L1)
__global__ __launch_bounds__(256) void decode(
    const float* __restrict__ part0, const float* __restrict__ part1,
    const float* __restrict__ dyn_b, const float* __restrict__ anchor0,
    const float* __restrict__ anchor1, float* __restrict__ out_coarse0,
    float* __restrict__ out_coarse1, float* __restrict__ out_regbox0,
    float* __restrict__ out_regbox1, float2* __restrict__ sem0,
    float2* __restrict__ sem1) {
  int bx = blockIdx.x;
  int n = blockIdx.y;
  const float* part;
  const float* anchor;
  float* out_coarse;
  float* out_regbox;
  float2* sem_ws;
  int Mtot, H, W, P, level;
  if (bx < 60) {
    part = part0; anchor = anchor0; out_coarse = out_coarse0;
    out_regbox = out_regbox0; sem_ws = sem0;
    Mtot = M0c; H = 100; W = 152; P = P0c; level = 0;
  } else {
    bx -= 60;
    part = part1; anchor = anchor1; out_coarse = out_coarse1;
    out_regbox = out_regbox1; sem_ws = sem1;
    Mtot = M1c; H = 50; W = 76; P = P1c; level = 1;
  }
  int p = bx * 256 + threadIdx.x;
  if (p >= P) return;
  int m = n * P + p;
  float pr[38];
  {
    const float* q0 = part + (size_t)m * NCOMB;
    const float* q1 = part + ((size_t)Mtot + m) * NCOMB;
    const float* q2 = part + ((size_t)2 * Mtot + m) * NCOMB;
#pragma unroll
    for (int o = 0; o < 38; ++o) pr[o] = q0[o] + q1[o] + q2[o];
#pragma unroll
    for (int o = 0; o < DYN_CH; ++o) pr[o] += dyn_b[o];
  }
  const float* an = anchor + (size_t)n * 4 * P + p;
  float cb[4];
#pragma unroll
  for (int k = 0; k < 4; ++k) cb[k] = an[(size_t)k * P] + pr[k];
  float* oc = out_coarse + (size_t)n * 4 * P + p;
#pragma unroll
  for (int k = 0; k < 4; ++k) oc[(size_t)k * P] = cb[k];

  float thr_y = (cb[3] - cb[1]) * 0.25f;
  float thr_x = (cb[2] - cb[0]) * 0.25f;
  float bo[4];
#pragma unroll
  for (int j = 0; j < 4; ++j) {
    float thr = (j & 1) ? thr_x : thr_y;
    float b = pr[4 + j];
    float extra = fmaxf(b - thr, 0.f) + fminf(b + thr, 0.f);
    bo[j] = b - extra;
  }
  float cx = 0.5f * (cb[0] + cb[2]);
  float cy = 0.5f * (cb[1] + cb[3]);
  float bp[8] = {cb[0], cy + bo[0], cx + bo[1], cb[1],
                 cb[2], cy + bo[2], cx + bo[3], cb[3]};

  int nbase = n * P;
  int nbaseLo = n * P0c;
  float rb[4];
#pragma unroll
  for (int pt = 0; pt < 4; ++pt) {
    float hi = samp48(part, Mtot, nbase, W, H, bp[2 * pt], bp[2 * pt + 1],
                      DYN_CH + pt);
    float val;
    if (level == 0) {
      val = hi;
    } else {
      float lo = 0.5f * samp48(part0, M0c, nbaseLo, 152, 100, bp[2 * pt] * 2.f,
                               bp[2 * pt + 1] * 2.f, DYN_CH + pt);
      float e0 = pr[26 + 2 * pt], e1 = pr[26 + 2 * pt + 1];
      float mx = fmaxf(e0, e1);
      float w0 = expf(e0 - mx), w1 = expf(e1 - mx);
      val = (lo * w0 + hi * w1) / (w0 + w1);
    }
    rb[pt] = val;
  }
  float* orb = out_regbox + (size_t)n * 4 * P + p;
  orb[0] = bp[0] + rb[0];
  orb[(size_t)P] = bp[3] + rb[1];
  orb[(size_t)2 * P] = bp[4] + rb[2];
  orb[(size_t)3 * P] = bp[7] + rb[3];

  float sx[9] = {cb[0], cb[0], cb[0], cx, cx, cx, cb[2], cb[2], cb[2]};
  float sy[9] = {cb[1], cy, cb[3], cb[1], cy, cb[3], cb[1], cy, cb[3]};
#pragma unroll
  for (int k = 0; k < 9; ++k) {
    float2 s = {sx[k] + pr[8 + 2 * k], sy[k] + pr[8 + 2 * k + 1]};
    sem_ws[(size_t)k * Mtot + m] = s;
  }
}

// ------------- gather: pixel-major map, wave = 1 px, lane = cls (+16 tail)
__global__ __launch_bounds__(256) void cls_gather_f(
    const __hip_bfloat16* __restrict__ map0,
    const __hip_bfloat16* __restrict__ map1, const float2* __restrict__ sem0,
    const float2* __restrict__ sem1, const float* __restrict__ bias,
    float* __restrict__ outc0, float* __restrict__ outc1) {
  int b = blockIdx.x;
  const __hip_bfloat16* map;
  const float2* sem;
  float* out;
  int Mtot, P, W, H;
  if (b < 7600) { map = map0; sem = sem0; out = outc0; Mtot = M0c; P = P0c; W = 152; H = 100; }
  else { b -= 7600; map = map1; sem = sem1; out = outc1; Mtot = M1c; P = P1c; W = 76; H = 50; }
  int lane = threadIdx.x & 63;
  int m = b * 4 + (threadIdx.x >> 6);
  if (m >= Mtot) return;
  int n = m / P;
  int p = m - n * P;
  int nbase = n * P;

  int base[9], dX[9], dYW[9];
  float w00[9], w01[9], w10[9], w11[9];
#pragma unroll
  for (int pt = 0; pt < 9; ++pt) {
    float2 s = sem[(size_t)pt * Mtot + m];
    float xc = fminf(fmaxf(s.x, 0.f), (float)(W - 1));
    float yc = fminf(fmaxf(s.y, 0.f), (float)(H - 1));
    float x0f = floorf(xc), y0f = floorf(yc);
    float fx = xc - x0f, fy = yc - y0f;
    int x0 = (int)x0f, y0 = (int)y0f;
    int x1 = min(x0 + 1, W - 1), y1 = min(y0 + 1, H - 1);
    base[pt] = nbase + y0 * W + x0;
    dX[pt] = x1 - x0;
    dYW[pt] = (y1 - y0) * W;
    w00[pt] = (1.f - fx) * (1.f - fy);
    w01[pt] = fx * (1.f - fy);
    w10[pt] = (1.f - fx) * fy;
    w11[pt] = fx * fy;
  }
  float acc0 = 0.f, acc1 = 0.f;
#pragma unroll
  for (int pt = 0; pt < 9; ++pt) {
    const __hip_bfloat16* pl = map + (size_t)base[pt] * CLS_CH + pt * 80 + lane;
    size_t o01 = (size_t)dX[pt] * CLS_CH;
    size_t o10 = (size_t)dYW[pt] * CLS_CH;
    float v00 = __bfloat162float(pl[0]);
    float v01 = __bfloat162float(pl[o01]);
    float v10 = __bfloat162float(pl[o10]);
    float v11 = __bfloat162float(pl[o10 + o01]);
    acc0 += w00[pt] * v00 + w01[pt] * v01 + w10[pt] * v10 + w11[pt] * v11;
    if (lane < 16) {
      float u00 = __bfloat162float(pl[64]);
      float u01 = __bfloat162float(pl[o01 + 64]);
      float u10 = __bfloat162float(pl[o10 + 64]);
      float u11 = __bfloat162float(pl[o10 + o01 + 64]);
      acc1 += w00[pt] * u00 + w01[pt] * u01 + w10[pt] * u10 + w11[pt] * u11;
    }
  }
  float* on = out + (size_t)n * NUM_CLASSES * P + p;
  on[(size_t)lane * P] = acc0 + bias[lane];
  if (lane < 16) on[(size_t)(lane + 64) * P] = acc1 + bias[lane + 64];
}

// ---------------------------------------------------------------------- launch
extern "C" void kernel_launch(void* const* d_in, const int* in_sizes, int n_in,
                              void* d_out, int out_size, void* d_ws,
                              size_t ws_size, hipStream_t stream) {
  const float* reg_feat0 = (const float*)d_in[0];
  const float* reg_feat1 = (const float*)d_in[1];
  const float* cls_feat0 = (const float*)d_in[2];
  const float* cls_feat1 = (const float*)d_in[3];
  const float* anchor0 = (const float*)d_in[4];
  const float* anchor1 = (const float*)d_in[5];
  const float* dyn_w = (const float*)d_in[6];
  const float* dyn_b = (const float*)d_in[7];
  const float* reg_w = (const float*)d_in[8];
  const float* cls_w = (const float*)d_in[9];
  const float* cls_b = (const float*)d_in[10];

  float* out = (float*)d_out;
  float* out_cls0 = out;
  float* out_cls1 = out_cls0 + (size_t)N_BATCH * NUM_CLASSES * P0c;
  float* out_coarse0 = out_cls1 + (size_t)N_BATCH * NUM_CLASSES * P1c;
  float* out_coarse1 = out_coarse0 + (size_t)N_BATCH * 4 * P0c;
  float* out_reg0 = out_coarse1 + (size_t)N_BATCH * 4 * P1c;
  float* out_reg1 = out_reg0 + (size_t)N_BATCH * 4 * P0c;

  // ---- workspace layout (bytes)
  char* w = (char*)d_ws;
  __hip_bfloat16* bpack = (__hip_bfloat16*)w;   w += 368640;
  __hip_bfloat16* wpack = (__hip_bfloat16*)w;   w += 221184;
  float2* sem0 = (float2*)w;                    w += 2188800;   // 9*M0*8
  float2* sem1 = (float2*)w;                    w += 547200;    // 9*M1*8
  char* apack_base = w;
  __hip_bfloat16* apack0 = (__hip_bfloat16*)w;  w += 15597568;  // 119*8192*16
  __hip_bfloat16* apack1 = (__hip_bfloat16*)w;  w += 3932160;   // 30*8192*16
  __hip_bfloat16* rpack0 = (__hip_bfloat16*)w;  w += 15597568;  // tiled now
  __hip_bfloat16* rpack1 = (__hip_bfloat16*)w;  w += 3932160;
  float* part1 = (float*)w;                     w += 4377600;   // 3*M1*48*4
  __hip_bfloat16* map0 = (__hip_bfloat16*)w;    w += 43776000;  // M0*720*2
  __hip_bfloat16* map1 = (__hip_bfloat16*)w;    w += 10944000;  // M1*720*2
  // part0 (17510400 B) aliases apack0+apack1 (19529728 B), dead after gemm.
  float* part0 = (float*)apack_base;

  hipLaunchKernelGGL(pack_feat, dim3(2528), dim3(256), 0, stream, cls_feat0,
                     cls_feat1, reg_feat0, reg_feat1, cls_w, dyn_w, reg_w,
                     apack0, apack1, rpack0, rpack1, bpack, wpack);
  hipLaunchKernelGGL(cls_gemm_mfma, dim3(MT0c + MT1c, 9), dim3(256), 0, stream,
                     (const uint4*)apack0, (const uint4*)apack1,
                     (const uint4*)bpack, map0, map1);
  hipLaunchKernelGGL(dyn_reg_conv_mfma, dim3(CT0c + CT1c, 3), dim3(256), 0,
                     stream, (const uint4*)rpack0, (const uint4*)rpack1,
                     (const uint4*)wpack, part0, part1);
  hipLaunchKernelGGL(decode, dim3(75, N_BATCH), dim3(256), 0, stream, part0,
                     part1, dyn_b, anchor0, anchor1, out_coarse0, out_coarse1,
                     out_reg0, out_reg1, sem0, sem1);
  hipLaunchKernelGGL(cls_gather_f, dim3(7600 + 1900), dim3(256), 0, stream,
                     map0, map1, sem0, sem1, cls_b, out_cls0, out_cls1);
}

// Round 7
// 277.964 us; speedup vs baseline: 1.3748x; 1.0131x over previous
//
#include <hip/hip_runtime.h>
#include <hip/hip_bf16.h>
#include <cstdint>

#define N_BATCH 2
#define C_IN 256
#define DYN_CH 34
#define CLS_CH 720
#define NUM_CLASSES 80
#define NCOMB 48

#define P0c 15200
#define P1c 3800
#define M0c 30400
#define M1c 7600
#define MT0c 119
#define MT1c 30
#define CT0c 475
#define CT1c 119

typedef __attribute__((ext_vector_type(8))) short short8;   // 8 bf16
typedef __attribute__((ext_vector_type(4))) float f32x4;

typedef const unsigned int __attribute__((address_space(1)))* gas1_t;
typedef unsigned int __attribute__((address_space(3)))* las3_t;

__device__ __forceinline__ void async_ld16(const void* g, void* l) {
  __builtin_amdgcn_global_load_lds((gas1_t)g, (las3_t)l, 16, 0, 0);
}

// ---------------- pack_feat: all 4 feature packs (tiled layout) + weight packs
__global__ __launch_bounds__(256) void pack_feat(
    const float* __restrict__ cls0, const float* __restrict__ cls1,
    const float* __restrict__ reg0, const float* __restrict__ reg1,
    const float* __restrict__ cls_w, const float* __restrict__ dyn_w,
    const float* __restrict__ reg_w, __hip_bfloat16* __restrict__ a0,
    __hip_bfloat16* __restrict__ a1, __hip_bfloat16* __restrict__ r0,
    __hip_bfloat16* __restrict__ r1, __hip_bfloat16* __restrict__ bpack,
    __hip_bfloat16* __restrict__ wpack) {
  int b = blockIdx.x;
  if (b >= 2384) {
    b -= 2384;
    if (b < 90) {  // cls weights -> bpack [ntile][kcg][och]
      int u = b * 256 + threadIdx.x;
      if (u >= 9 * 32 * 80) return;
      int ntile = u / 2560;
      int rem = u % 2560;
      int kcg = rem / 80;
      int ochl = rem % 80;
      int och = ntile * 80 + ochl;
      const float* wr = cls_w + (size_t)och * C_IN + kcg * 8;
      __hip_bfloat16 tmp[8];
#pragma unroll
      for (int c = 0; c < 8; ++c) tmp[c] = __float2bfloat16(wr[c]);
      *(uint4*)(bpack + (size_t)u * 8) = *(const uint4*)tmp;
    } else {  // dyn+reg weights -> wpack swizzled [chunk][n][slot]
      int u = (b - 90) * 256 + threadIdx.x;
      if (u >= 13824) return;
      int j = u / 768;
      int r = u % 768;
      int n = r / 16;
      int s = r % 16;
      int ku = j * 16 + (s ^ (n & 7));
      int k0 = ku * 8;
      int tap = k0 >> 8;
      int c0 = k0 & 255;
      __hip_bfloat16 tmp[8];
#pragma unroll
      for (int i = 0; i < 8; ++i) {
        int c = c0 + i;
        float v = 0.f;
        if (n < DYN_CH) v = dyn_w[((size_t)n * C_IN + c) * 9 + tap];
        else if (n < DYN_CH + 4 && tap == 4)
          v = reg_w[(size_t)(n - DYN_CH) * C_IN + c];
        tmp[i] = __float2bfloat16(v);
      }
      *(uint4*)(wpack + (size_t)u * 8) = *(const uint4*)tmp;
    }
    return;
  }
  int j = b & 7;
  int mtg = b >> 3;
  const float* src;
  __hip_bfloat16* dst;
  int P, Mtot, mtile;
  if (mtg < 119)      { src = cls0; dst = a0; P = P0c; Mtot = M0c; mtile = mtg; }
  else if (mtg < 149) { src = cls1; dst = a1; P = P1c; Mtot = M1c; mtile = mtg - 119; }
  else if (mtg < 268) { src = reg0; dst = r0; P = P0c; Mtot = M0c; mtile = mtg - 149; }
  else                { src = reg1; dst = r1; P = P1c; Mtot = M1c; mtile = mtg - 268; }
  int wave = threadIdx.x >> 6;
  int lane = threadIdx.x & 63;
  int kcg = j * 4 + wave;
  int c0 = kcg * 8;
  int m4 = mtile * 256 + lane * 4;
  uint4* du = (uint4*)dst + (size_t)mtile * 8192 + (size_t)kcg * 256 + lane * 4;
  if (m4 < Mtot) {
    int n = m4 / P;
    int p = m4 - n * P;
    const float* sp = src + ((size_t)n * C_IN + c0) * P + p;
    float4 f[8];
#pragma unroll
    for (int c = 0; c < 8; ++c) f[c] = *(const float4*)(sp + (size_t)c * P);
#pragma unroll
    for (int i = 0; i < 4; ++i) {
      union { uint4 u; __hip_bfloat16 h[8]; } o;
#pragma unroll
      for (int c = 0; c < 8; ++c) {
        float v = (i == 0) ? f[c].x : (i == 1) ? f[c].y : (i == 2) ? f[c].z : f[c].w;
        o.h[c] = __float2bfloat16(v);
      }
      du[i] = o.u;
    }
  } else {
    uint4 z = {0u, 0u, 0u, 0u};
#pragma unroll
    for (int i = 0; i < 4; ++i) du[i] = z;
  }
}

// ------------------- cls 1x1 bf16 MFMA GEMM -> bf16 map pixel-major [m][720]
__global__ __launch_bounds__(256) void cls_gemm_mfma(
    const uint4* __restrict__ Ap0, const uint4* __restrict__ Ap1,
    const uint4* __restrict__ Bp, __hip_bfloat16* __restrict__ out0,
    __hip_bfloat16* __restrict__ out1) {
  __shared__ uint4 Ash[1024];
  __shared__ uint4 Bsh[320];
  int tid = threadIdx.x;
  int wave = tid >> 6;
  int lane = tid & 63;
  int l15 = lane & 15;
  int kq = lane >> 4;
  int mtile = blockIdx.x;
  int ntile = blockIdx.y;

  const uint4* Ap;
  __hip_bfloat16* out;
  int Mtot;
  if (mtile < MT0c) { Ap = Ap0; out = out0; Mtot = M0c; }
  else              { mtile -= MT0c; Ap = Ap1; out = out1; Mtot = M1c; }

  const uint4* Ab = Ap + (size_t)mtile * 8192;
  const uint4* Bb = Bp + (size_t)ntile * 2560;

  f32x4 acc[4][5];
#pragma unroll
  for (int i = 0; i < 4; ++i)
#pragma unroll
    for (int j = 0; j < 5; ++j) acc[i][j] = (f32x4)0.f;

  for (int kb = 0; kb < 8; ++kb) {
    const uint4* Aslab = Ab + kb * 1024;
#pragma unroll
    for (int i = 0; i < 4; ++i) {
      int j = wave * 4 + i;
      async_ld16(Aslab + j * 64 + lane, &Ash[j * 64]);
    }
    const uint4* Bslab = Bb + kb * 320;
    for (int j = wave; j < 5; j += 4) {
      async_ld16(Bslab + j * 64 + lane, &Bsh[j * 64]);
    }
    __syncthreads();

    short8 a[4], b[5];
    const uint4* Ar = &Ash[kq * 256 + wave * 64 + l15];
#pragma unroll
    for (int mi = 0; mi < 4; ++mi) a[mi] = *(const short8*)&Ar[mi * 16];
    const uint4* Br = &Bsh[kq * 80 + l15];
#pragma unroll
    for (int ni = 0; ni < 5; ++ni) b[ni] = *(const short8*)&Br[ni * 16];
#pragma unroll
    for (int mi = 0; mi < 4; ++mi)
#pragma unroll
      for (int ni = 0; ni < 5; ++ni)
        acc[mi][ni] = __builtin_amdgcn_mfma_f32_16x16x32_bf16(
            a[mi], b[ni], acc[mi][ni], 0, 0, 0);
    __syncthreads();
  }

  int gbase = mtile * 256 + wave * 64;
#pragma unroll
  for (int mi = 0; mi < 4; ++mi) {
#pragma unroll
    for (int r = 0; r < 4; ++r) {
      int g = gbase + mi * 16 + kq * 4 + r;
      if (g >= Mtot) continue;
      __hip_bfloat16* orow = out + (size_t)g * CLS_CH + ntile * 80 + l15;
#pragma unroll
      for (int ni = 0; ni < 5; ++ni)
        orow[ni * 16] = __float2bfloat16(acc[mi][ni][r]);
    }
  }
}

// ---------- dyn3x3 + reg1x1 fused implicit-GEMM MFMA, split-K=3, both levels
__global__ __launch_bounds__(256) void dyn_reg_conv_mfma(
    const uint4* __restrict__ rp0, const uint4* __restrict__ rp1,
    const uint4* __restrict__ wp, float* __restrict__ part0,
    float* __restrict__ part1) {
  __shared__ uint4 Bs[768];
  int tid = threadIdx.x;
  int wave = tid >> 6;
  int lane = tid & 63;
  int l15 = lane & 15;
  int kq = lane >> 4;
  int seg = blockIdx.y;
  int bx = blockIdx.x;

  const uint4* rp;
  float* part;
  int Mtot, P, W, H;
  if (bx < CT0c) { rp = rp0; part = part0; Mtot = M0c; P = P0c; W = 152; H = 100; }
  else { bx -= CT0c; rp = rp1; part = part1; Mtot = M1c; P = P1c; W = 76; H = 50; }

  int m = bx * 64 + wave * 16 + l15;
  bool mval = (m < Mtot);
  int mc = mval ? m : 0;
  int n = mc / P;
  int rem = mc - n * P;
  int y = rem / W;
  int x = rem - y * W;

  f32x4 acc[3];
#pragma unroll
  for (int i = 0; i < 3; ++i) acc[i] = (f32x4)0.f;

  for (int jj = 0; jj < 6; ++jj) {
    int j = seg * 6 + jj;
    const uint4* wsrc = wp + (size_t)j * 768 + wave * 192;
#pragma unroll
    for (int i = 0; i < 3; ++i)
      async_ld16(wsrc + i * 64 + lane, &Bs[wave * 192 + i * 64]);

    int tap = j >> 1;
    int cb8 = (j & 1) * 16;
    int dy = tap / 3 - 1, dx = tap % 3 - 1;
    int sy = y + dy, sx = x + dx;
    bool val = mval && ((unsigned)sy < (unsigned)H) && ((unsigned)sx < (unsigned)W);
    int sm = m + dy * W + dx;
    int smc = val ? sm : 0;
    size_t tbase = (size_t)(smc >> 8) * 8192 + (smc & 255);
    uint4 a[4];
#pragma unroll
    for (int t = 0; t < 4; ++t) {
      uint4 v = {0u, 0u, 0u, 0u};
      if (val) v = rp[tbase + (size_t)(cb8 + t * 4 + kq) * 256];
      a[t] = v;
    }
    __syncthreads();
#pragma unroll
    for (int t = 0; t < 4; ++t) {
#pragma unroll
      for (int ni = 0; ni < 3; ++ni) {
        int nn = ni * 16 + l15;
        short8 bf = *(const short8*)&Bs[nn * 16 + ((t * 4 + kq) ^ (nn & 7))];
        acc[ni] = __builtin_amdgcn_mfma_f32_16x16x32_bf16(
            *(short8*)&a[t], bf, acc[ni], 0, 0, 0);
      }
    }
    __syncthreads();
  }

  int mrow = bx * 64 + wave * 16 + kq * 4;
#pragma unroll
  for (int r = 0; r < 4; ++r) {
    int mm = mrow + r;
    if (mm >= Mtot) continue;
    float* dst = part + ((size_t)seg * Mtot + mm) * NCOMB + l15;
#pragma unroll
    for (int ni = 0; ni < 3; ++ni) dst[ni * 16] = acc[ni][r];
  }
}

// -------------------- bilinear sample of combined-map channel (3 K-segments)
__device__ __forceinline__ float samp48(const float* __restrict__ part,
                                        int Mtot, int nbase, int W, int H,
                                        float px, float py, int ch) {
  float xc = fminf(fmaxf(px, 0.f), (float)(W - 1));
  float yc = fminf(fmaxf(py, 0.f), (float)(H - 1));
  float x0f = floorf(xc), y0f = floorf(yc);
  float fx = xc - x0f, fy = yc - y0f;
  int x0 = (int)x0f, y0 = (int)y0f;
  int x1 = min(x0 + 1, W - 1), y1 = min(y0 + 1, H - 1);
  size_t m00 = (size_t)(nbase + y0 * W + x0);
  size_t m01 = (size_t)(nbase + y0 * W + x1);
  size_t m10 = (size_t)(nbase + y1 * W + x0);
  size_t m11 = (size_t)(nbase + y1 * W + x1);
  float v00 = 0.f, v01 = 0.f, v10 = 0.f, v11 = 0.f;
#pragma unroll
  for (int s = 0; s < 3; ++s) {
    size_t off = (size_t)s * Mtot;
    v00 += part[(off + m00) * NCOMB + ch];
    v01 += part[(off + m01) * NCOMB + ch];
    v10 += part[(off + m10) * NCOMB + ch];
    v11 += part[(off + m11) * NCOMB + ch];
  }
  return v00 * (1.f - fx) * (1.f - fy) + v01 * fx * (1.f - fy) +
         v10 * (1.f - fx) * fy + v11 * fx * fy;
}

// ---------------- decode, both levels fused (bx<60 -> L0, else L1)
__global__ __launch_bounds__(256) void decode(
    const float* __restrict__ part0, const float* __restrict__ part1,
    const float* __restrict__ dyn_b, const float* __restrict__ anchor0,
    const float* __restrict__ anchor1, float* __restrict__ out_coarse0,
    float* __restrict__ out_coarse1, float* __restrict__ out_regbox0,
    float* __restrict__ out_regbox1, float2* __restrict__ sem0,
    float2* __restrict__ sem1) {
  int bx = blockIdx.x;
  int n = blockIdx.y;
  const float* part;
  const float* anchor;
  float* out_coarse;
  float* out_regbox;
  float2* sem_ws;
  int Mtot, H, W, P, level;
  if (bx < 60) {
    part = part0; anchor = anchor0; out_coarse = out_coarse0;
    out_regbox = out_regbox0; sem_ws = sem0;
    Mtot = M0c; H = 100; W = 152; P = P0c; level = 0;
  } else {
    bx -= 60;
    part = part1; anchor = anchor1; out_coarse = out_coarse1;
    out_regbox = out_regbox1; sem_ws = sem1;
    Mtot = M1c; H = 50; W = 76; P = P1c; level = 1;
  }
  int p = bx * 256 + threadIdx.x;
  if (p >= P) return;
  int m = n * P + p;
  float pr[38];
  {
    const float* q0 = part + (size_t)m * NCOMB;
    const float* q1 = part + ((size_t)Mtot + m) * NCOMB;
    const float* q2 = part + ((size_t)2 * Mtot + m) * NCOMB;
#pragma unroll
    for (int o = 0; o < 38; ++o) pr[o] = q0[o] + q1[o] + q2[o];
#pragma unroll
    for (int o = 0; o < DYN_CH; ++o) pr[o] += dyn_b[o];
  }
  const float* an = anchor + (size_t)n * 4 * P + p;
  float cb[4];
#pragma unroll
  for (int k = 0; k < 4; ++k) cb[k] = an[(size_t)k * P] + pr[k];
  float* oc = out_coarse + (size_t)n * 4 * P + p;
#pragma unroll
  for (int k = 0; k < 4; ++k) oc[(size_t)k * P] = cb[k];

  float thr_y = (cb[3] - cb[1]) * 0.25f;
  float thr_x = (cb[2] - cb[0]) * 0.25f;
  float bo[4];
#pragma unroll
  for (int j = 0; j < 4; ++j) {
    float thr = (j & 1) ? thr_x : thr_y;
    float b = pr[4 + j];
    float extra = fmaxf(b - thr, 0.f) + fminf(b + thr, 0.f);
    bo[j] = b - extra;
  }
  float cx = 0.5f * (cb[0] + cb[2]);
  float cy = 0.5f * (cb[1] + cb[3]);
  float bp[8] = {cb[0], cy + bo[0], cx + bo[1], cb[1],
                 cb[2], cy + bo[2], cx + bo[3], cb[3]};

  int nbase = n * P;
  int nbaseLo = n * P0c;
  float rb[4];
#pragma unroll
  for (int pt = 0; pt < 4; ++pt) {
    float hi = samp48(part, Mtot, nbase, W, H, bp[2 * pt], bp[2 * pt + 1],
                      DYN_CH + pt);
    float val;
    if (level == 0) {
      val = hi;
    } else {
      float lo = 0.5f * samp48(part0, M0c, nbaseLo, 152, 100, bp[2 * pt] * 2.f,
                               bp[2 * pt + 1] * 2.f, DYN_CH + pt);
      float e0 = pr[26 + 2 * pt], e1 = pr[26 + 2 * pt + 1];
      float mx = fmaxf(e0, e1);
      float w0 = expf(e0 - mx), w1 = expf(e1 - mx);
      val = (lo * w0 + hi * w1) / (w0 + w1);
    }
    rb[pt] = val;
  }
  float* orb = out_regbox + (size_t)n * 4 * P + p;
  orb[0] = bp[0] + rb[0];
  orb[(size_t)P] = bp[3] + rb[1];
  orb[(size_t)2 * P] = bp[4] + rb[2];
  orb[(size_t)3 * P] = bp[7] + rb[3];

  float sx[9] = {cb[0], cb[0], cb[0], cx, cx, cx, cb[2], cb[2], cb[2]};
  float sy[9] = {cb[1], cy, cb[3], cb[1], cy, cb[3], cb[1], cy, cb[3]};
#pragma unroll
  for (int k = 0; k < 9; ++k) {
    float2 s = {sx[k] + pr[8 + 2 * k], sy[k] + pr[8 + 2 * k + 1]};
    sem_ws[(size_t)k * Mtot + m] = s;
  }
}

// ------------- gather: pixel-major map, wave = 1 px, lane = cls (+16 tail)
// XCD swizzle for L2 locality; 3-pt load groups for MLP; LDS-transposed writes
__global__ __launch_bounds__(256) void cls_gather_f(
    const __hip_bfloat16* __restrict__ map0,
    const __hip_bfloat16* __restrict__ map1, const float2* __restrict__ sem0,
    const float2* __restrict__ sem1, const float* __restrict__ bias,
    float* __restrict__ outc0, float* __restrict__ outc1) {
  __shared__ float lds[NUM_CLASSES * 4];
  // grid = 9504 (padded); bijection [0,9504): consecutive logical blocks on 1 XCD
  int b = (blockIdx.x & 7) * 1188 + (blockIdx.x >> 3);
  if (b >= 9500) return;
  const __hip_bfloat16* map;
  const float2* sem;
  float* out;
  int Mtot, P, W, H;
  if (b < 7600) { map = map0; sem = sem0; out = outc0; Mtot = M0c; P = P0c; W = 152; H = 100; }
  else { b -= 7600; map = map1; sem = sem1; out = outc1; Mtot = M1c; P = P1c; W = 76; H = 50; }
  int lane = threadIdx.x & 63;
  int wv = threadIdx.x >> 6;
  int m = b * 4 + wv;            // P,M div by 4: no tail, no n-straddle per block
  int n = m / P;
  int p = m - n * P;
  int nbase = n * P;
  bool hi = lane < 16;

  // ---- hoisted per-point address/weight computation (int32 offsets)
  float2 sv[9];
#pragma unroll
  for (int pt = 0; pt < 9; ++pt) sv[pt] = sem[(size_t)pt * Mtot + m];
  int bidx[9], o01[9], o10[9];
  float w00[9], w01[9], w10[9], w11[9];
#pragma unroll
  for (int pt = 0; pt < 9; ++pt) {
    float xc = fminf(fmaxf(sv[pt].x, 0.f), (float)(W - 1));
    float yc = fminf(fmaxf(sv[pt].y, 0.f), (float)(H - 1));
    float x0f = floorf(xc), y0f = floorf(yc);
    float fx = xc - x0f, fy = yc - y0f;
    int x0 = (int)x0f, y0 = (int)y0f;
    int x1 = min(x0 + 1, W - 1), y1 = min(y0 + 1, H - 1);
    bidx[pt] = (nbase + y0 * W + x0) * CLS_CH + pt * 80 + lane;
    o01[pt] = (x1 - x0) * CLS_CH;
    o10[pt] = (y1 - y0) * W * CLS_CH;
    w00[pt] = (1.f - fx) * (1.f - fy);
    w01[pt] = fx * (1.f - fy);
    w10[pt] = (1.f - fx) * fy;
    w11[pt] = fx * fy;
  }
  float acc0 = 0.f, acc1 = 0.f;
  // ---- 3 groups of 3 pts: issue 12(+12) loads, then accumulate
#pragma unroll
  for (int g = 0; g < 3; ++g) {
    float v00[3], v01[3], v10[3], v11[3];
    float u00[3], u01[3], u10[3], u11[3];
#pragma unroll
    for (int q = 0; q < 3; ++q) {
      int pt = g * 3 + q;
      const __hip_bfloat16* pl = map + bidx[pt];
      v00[q] = __bfloat162float(pl[0]);
      v01[q] = __bfloat162float(pl[o01[pt]]);
      v10[q] = __bfloat162float(pl[o10[pt]]);
      v11[q] = __bfloat162float(pl[o10[pt] + o01[pt]]);
      if (hi) {
        u00[q] = __bfloat162float(pl[64]);
        u01[q] = __bfloat162float(pl[o01[pt] + 64]);
        u10[q] = __bfloat162float(pl[o10[pt] + 64]);
        u11[q] = __bfloat162float(pl[o10[pt] + o01[pt] + 64]);
      }
    }
#pragma unroll
    for (int q = 0; q < 3; ++q) {
      int pt = g * 3 + q;
      acc0 += w00[pt] * v00[q] + w01[pt] * v01[q] + w10[pt] * v10[q] +
              w11[pt] * v11[q];
      if (hi)
        acc1 += w00[pt] * u00[q] + w01[pt] * u01[q] + w10[pt] * u10[q] +
                w11[pt] * u11[q];
    }
  }
  // ---- LDS transpose -> coalesced float4 writes (cls rows, 4 px each)
  lds[lane * 4 + wv] = acc0 + bias[lane];
  if (hi) lds[(64 + lane) * 4 + wv] = acc1 + bias[64 + lane];
  __syncthreads();
  int tid = threadIdx.x;
  if (tid < NUM_CLASSES) {
    float4 v = *(const float4*)&lds[tid * 4];
    int p0 = b * 4 - n * P;  // first pixel of block within image n
    *(float4*)&out[((size_t)n * NUM_CLASSES + tid) * P + p0] = v;
  }
}

// ---------------------------------------------------------------------- launch
extern "C" void kernel_launch(void* const* d_in, const int* in_sizes, int n_in,
                              void* d_out, int out_size, void* d_ws,
                              size_t ws_size, hipStream_t stream) {
  const float* reg_feat0 = (const float*)d_in[0];
  const float* reg_feat1 = (const float*)d_in[1];
  const float* cls_feat0 = (const float*)d_in[2];
  const float* cls_feat1 = (const float*)d_in[3];
  const float* anchor0 = (const float*)d_in[4];
  const float* anchor1 = (const float*)d_in[5];
  const float* dyn_w = (const float*)d_in[6];
  const float* dyn_b = (const float*)d_in[7];
  const float* reg_w = (const float*)d_in[8];
  const float* cls_w = (const float*)d_in[9];
  const float* cls_b = (const float*)d_in[10];

  float* out = (float*)d_out;
  float* out_cls0 = out;
  float* out_cls1 = out_cls0 + (size_t)N_BATCH * NUM_CLASSES * P0c;
  float* out_coarse0 = out_cls1 + (size_t)N_BATCH * NUM_CLASSES * P1c;
  float* out_coarse1 = out_coarse0 + (size_t)N_BATCH * 4 * P0c;
  float* out_reg0 = out_coarse1 + (size_t)N_BATCH * 4 * P1c;
  float* out_reg1 = out_reg0 + (size_t)N_BATCH * 4 * P0c;

  // ---- workspace layout (bytes)
  char* w = (char*)d_ws;
  __hip_bfloat16* bpack = (__hip_bfloat16*)w;   w += 368640;
  __hip_bfloat16* wpack = (__hip_bfloat16*)w;   w += 221184;
  float2* sem0 = (float2*)w;                    w += 2188800;   // 9*M0*8
  float2* sem1 = (float2*)w;                    w += 547200;    // 9*M1*8
  char* apack_base = w;
  __hip_bfloat16* apack0 = (__hip_bfloat16*)w;  w += 15597568;  // 119*8192*16
  __hip_bfloat16* apack1 = (__hip_bfloat16*)w;  w += 3932160;   // 30*8192*16
  __hip_bfloat16* rpack0 = (__hip_bfloat16*)w;  w += 15597568;  // tiled
  __hip_bfloat16* rpack1 = (__hip_bfloat16*)w;  w += 3932160;
  float* part1 = (float*)w;                     w += 4377600;   // 3*M1*48*4
  __hip_bfloat16* map0 = (__hip_bfloat16*)w;    w += 43776000;  // M0*720*2
  __hip_bfloat16* map1 = (__hip_bfloat16*)w;    w += 10944000;  // M1*720*2
  // part0 (17510400 B) aliases apack0+apack1 (19529728 B), dead after gemm.
  float* part0 = (float*)apack_base;

  hipLaunchKernelGGL(pack_feat, dim3(2528), dim3(256), 0, stream, cls_feat0,
                     cls_feat1, reg_feat0, reg_feat1, cls_w, dyn_w, reg_w,
                     apack0, apack1, rpack0, rpack1, bpack, wpack);
  hipLaunchKernelGGL(cls_gemm_mfma, dim3(MT0c + MT1c, 9), dim3(256), 0, stream,
                     (const uint4*)apack0, (const uint4*)apack1,
                     (const uint4*)bpack, map0, map1);
  hipLaunchKernelGGL(dyn_reg_conv_mfma, dim3(CT0c + CT1c, 3), dim3(256), 0,
                     stream, (const uint4*)rpack0, (const uint4*)rpack1,
                     (const uint4*)wpack, part0, part1);
  hipLaunchKernelGGL(decode, dim3(75, N_BATCH), dim3(256), 0, stream, part0,
                     part1, dyn_b, anchor0, anchor1, out_coarse0, out_coarse1,
                     out_reg0, out_reg1, sem0, sem1);
  hipLaunchKernelGGL(cls_gather_f, dim3(9504), dim3(256), 0, stream, map0,
                     map1, sem0, sem1, cls_b, out_cls0, out_cls1);
}

// Round 8
// 258.447 us; speedup vs baseline: 1.4786x; 1.0755x over previous
//
#include <hip/hip_runtime.h>
#include <hip/hip_bf16.h>
#include <cstdint>

#define N_BATCH 2
#define C_IN 256
#define DYN_CH 34
#define CLS_CH 720
#define NUM_CLASSES 80
#define NCOMB 48

#define P0c 15200
#define P1c 3800
#define M0c 30400
#define M1c 7600
#define MT0c 119
#define MT1c 30
#define CT0c 475
#define CT1c 119

typedef __attribute__((ext_vector_type(8))) short short8;   // 8 bf16
typedef __attribute__((ext_vector_type(4))) float f32x4;

typedef const unsigned int __attribute__((address_space(1)))* gas1_t;
typedef unsigned int __attribute__((address_space(3)))* las3_t;

__device__ __forceinline__ void async_ld16(const void* g, void* l) {
  __builtin_amdgcn_global_load_lds((gas1_t)g, (las3_t)l, 16, 0, 0);
}

// ---------------- pack_feat: all 4 feature packs (tiled layout) + weight packs
__global__ __launch_bounds__(256) void pack_feat(
    const float* __restrict__ cls0, const float* __restrict__ cls1,
    const float* __restrict__ reg0, const float* __restrict__ reg1,
    const float* __restrict__ cls_w, const float* __restrict__ dyn_w,
    const float* __restrict__ reg_w, __hip_bfloat16* __restrict__ a0,
    __hip_bfloat16* __restrict__ a1, __hip_bfloat16* __restrict__ r0,
    __hip_bfloat16* __restrict__ r1, __hip_bfloat16* __restrict__ bpack,
    __hip_bfloat16* __restrict__ wpack) {
  int b = blockIdx.x;
  if (b >= 2384) {
    b -= 2384;
    if (b < 90) {  // cls weights -> bpack [ntile][kcg][och]
      int u = b * 256 + threadIdx.x;
      if (u >= 9 * 32 * 80) return;
      int ntile = u / 2560;
      int rem = u % 2560;
      int kcg = rem / 80;
      int ochl = rem % 80;
      int och = ntile * 80 + ochl;
      const float* wr = cls_w + (size_t)och * C_IN + kcg * 8;
      __hip_bfloat16 tmp[8];
#pragma unroll
      for (int c = 0; c < 8; ++c) tmp[c] = __float2bfloat16(wr[c]);
      *(uint4*)(bpack + (size_t)u * 8) = *(const uint4*)tmp;
    } else {  // dyn+reg weights -> wpack swizzled [chunk][n][slot]
      int u = (b - 90) * 256 + threadIdx.x;
      if (u >= 13824) return;
      int j = u / 768;
      int r = u % 768;
      int n = r / 16;
      int s = r % 16;
      int ku = j * 16 + (s ^ (n & 7));
      int k0 = ku * 8;
      int tap = k0 >> 8;
      int c0 = k0 & 255;
      __hip_bfloat16 tmp[8];
#pragma unroll
      for (int i = 0; i < 8; ++i) {
        int c = c0 + i;
        float v = 0.f;
        if (n < DYN_CH) v = dyn_w[((size_t)n * C_IN + c) * 9 + tap];
        else if (n < DYN_CH + 4 && tap == 4)
          v = reg_w[(size_t)(n - DYN_CH) * C_IN + c];
        tmp[i] = __float2bfloat16(v);
      }
      *(uint4*)(wpack + (size_t)u * 8) = *(const uint4*)tmp;
    }
    return;
  }
  int j = b & 7;
  int mtg = b >> 3;
  const float* src;
  __hip_bfloat16* dst;
  int P, Mtot, mtile;
  if (mtg < 119)      { src = cls0; dst = a0; P = P0c; Mtot = M0c; mtile = mtg; }
  else if (mtg < 149) { src = cls1; dst = a1; P = P1c; Mtot = M1c; mtile = mtg - 119; }
  else if (mtg < 268) { src = reg0; dst = r0; P = P0c; Mtot = M0c; mtile = mtg - 149; }
  else                { src = reg1; dst = r1; P = P1c; Mtot = M1c; mtile = mtg - 268; }
  int wave = threadIdx.x >> 6;
  int lane = threadIdx.x & 63;
  int kcg = j * 4 + wave;
  int c0 = kcg * 8;
  int m4 = mtile * 256 + lane * 4;
  uint4* du = (uint4*)dst + (size_t)mtile * 8192 + (size_t)kcg * 256 + lane * 4;
  if (m4 < Mtot) {
    int n = m4 / P;
    int p = m4 - n * P;
    const float* sp = src + ((size_t)n * C_IN + c0) * P + p;
    float4 f[8];
#pragma unroll
    for (int c = 0; c < 8; ++c) f[c] = *(const float4*)(sp + (size_t)c * P);
#pragma unroll
    for (int i = 0; i < 4; ++i) {
      union { uint4 u; __hip_bfloat16 h[8]; } o;
#pragma unroll
      for (int c = 0; c < 8; ++c) {
        float v = (i == 0) ? f[c].x : (i == 1) ? f[c].y : (i == 2) ? f[c].z : f[c].w;
        o.h[c] = __float2bfloat16(v);
      }
      du[i] = o.u;
    }
  } else {
    uint4 z = {0u, 0u, 0u, 0u};
#pragma unroll
    for (int i = 0; i < 4; ++i) du[i] = z;
  }
}

// ------------------- cls 1x1 bf16 MFMA GEMM -> bf16 map pixel-major [m][720]
__global__ __launch_bounds__(256) void cls_gemm_mfma(
    const uint4* __restrict__ Ap0, const uint4* __restrict__ Ap1,
    const uint4* __restrict__ Bp, __hip_bfloat16* __restrict__ out0,
    __hip_bfloat16* __restrict__ out1) {
  __shared__ uint4 Ash[1024];
  __shared__ uint4 Bsh[320];
  int tid = threadIdx.x;
  int wave = tid >> 6;
  int lane = tid & 63;
  int l15 = lane & 15;
  int kq = lane >> 4;
  int mtile = blockIdx.x;
  int ntile = blockIdx.y;

  const uint4* Ap;
  __hip_bfloat16* out;
  int Mtot;
  if (mtile < MT0c) { Ap = Ap0; out = out0; Mtot = M0c; }
  else              { mtile -= MT0c; Ap = Ap1; out = out1; Mtot = M1c; }

  const uint4* Ab = Ap + (size_t)mtile * 8192;
  const uint4* Bb = Bp + (size_t)ntile * 2560;

  f32x4 acc[4][5];
#pragma unroll
  for (int i = 0; i < 4; ++i)
#pragma unroll
    for (int j = 0; j < 5; ++j) acc[i][j] = (f32x4)0.f;

  for (int kb = 0; kb < 8; ++kb) {
    const uint4* Aslab = Ab + kb * 1024;
#pragma unroll
    for (int i = 0; i < 4; ++i) {
      int j = wave * 4 + i;
      async_ld16(Aslab + j * 64 + lane, &Ash[j * 64]);
    }
    const uint4* Bslab = Bb + kb * 320;
    for (int j = wave; j < 5; j += 4) {
      async_ld16(Bslab + j * 64 + lane, &Bsh[j * 64]);
    }
    __syncthreads();

    short8 a[4], b[5];
    const uint4* Ar = &Ash[kq * 256 + wave * 64 + l15];
#pragma unroll
    for (int mi = 0; mi < 4; ++mi) a[mi] = *(const short8*)&Ar[mi * 16];
    const uint4* Br = &Bsh[kq * 80 + l15];
#pragma unroll
    for (int ni = 0; ni < 5; ++ni) b[ni] = *(const short8*)&Br[ni * 16];
#pragma unroll
    for (int mi = 0; mi < 4; ++mi)
#pragma unroll
      for (int ni = 0; ni < 5; ++ni)
        acc[mi][ni] = __builtin_amdgcn_mfma_f32_16x16x32_bf16(
            a[mi], b[ni], acc[mi][ni], 0, 0, 0);
    __syncthreads();
  }

  int gbase = mtile * 256 + wave * 64;
#pragma unroll
  for (int mi = 0; mi < 4; ++mi) {
#pragma unroll
    for (int r = 0; r < 4; ++r) {
      int g = gbase + mi * 16 + kq * 4 + r;
      if (g >= Mtot) continue;
      __hip_bfloat16* orow = out + (size_t)g * CLS_CH + ntile * 80 + l15;
#pragma unroll
      for (int ni = 0; ni < 5; ++ni)
        orow[ni * 16] = __float2bfloat16(acc[mi][ni][r]);
    }
  }
}

// ---------- dyn3x3 + reg1x1 fused implicit-GEMM MFMA, split-K=3, both levels
__global__ __launch_bounds__(256) void dyn_reg_conv_mfma(
    const uint4* __restrict__ rp0, const uint4* __restrict__ rp1,
    const uint4* __restrict__ wp, float* __restrict__ part0,
    float* __restrict__ part1) {
  __shared__ uint4 Bs[768];
  int tid = threadIdx.x;
  int wave = tid >> 6;
  int lane = tid & 63;
  int l15 = lane & 15;
  int kq = lane >> 4;
  int seg = blockIdx.y;
  int bx = blockIdx.x;

  const uint4* rp;
  float* part;
  int Mtot, P, W, H;
  if (bx < CT0c) { rp = rp0; part = part0; Mtot = M0c; P = P0c; W = 152; H = 100; }
  else { bx -= CT0c; rp = rp1; part = part1; Mtot = M1c; P = P1c; W = 76; H = 50; }

  int m = bx * 64 + wave * 16 + l15;
  bool mval = (m < Mtot);
  int mc = mval ? m : 0;
  int n = mc / P;
  int rem = mc - n * P;
  int y = rem / W;
  int x = rem - y * W;

  f32x4 acc[3];
#pragma unroll
  for (int i = 0; i < 3; ++i) acc[i] = (f32x4)0.f;

  for (int jj = 0; jj < 6; ++jj) {
    int j = seg * 6 + jj;
    const uint4* wsrc = wp + (size_t)j * 768 + wave * 192;
#pragma unroll
    for (int i = 0; i < 3; ++i)
      async_ld16(wsrc + i * 64 + lane, &Bs[wave * 192 + i * 64]);

    int tap = j >> 1;
    int cb8 = (j & 1) * 16;
    int dy = tap / 3 - 1, dx = tap % 3 - 1;
    int sy = y + dy, sx = x + dx;
    bool val = mval && ((unsigned)sy < (unsigned)H) && ((unsigned)sx < (unsigned)W);
    int sm = m + dy * W + dx;
    int smc = val ? sm : 0;
    size_t tbase = (size_t)(smc >> 8) * 8192 + (smc & 255);
    uint4 a[4];
#pragma unroll
    for (int t = 0; t < 4; ++t) {
      uint4 v = {0u, 0u, 0u, 0u};
      if (val) v = rp[tbase + (size_t)(cb8 + t * 4 + kq) * 256];
      a[t] = v;
    }
    __syncthreads();
#pragma unroll
    for (int t = 0; t < 4; ++t) {
#pragma unroll
      for (int ni = 0; ni < 3; ++ni) {
        int nn = ni * 16 + l15;
        short8 bf = *(const short8*)&Bs[nn * 16 + ((t * 4 + kq) ^ (nn & 7))];
        acc[ni] = __builtin_amdgcn_mfma_f32_16x16x32_bf16(
            *(short8*)&a[t], bf, acc[ni], 0, 0, 0);
      }
    }
    __syncthreads();
  }

  int mrow = bx * 64 + wave * 16 + kq * 4;
#pragma unroll
  for (int r = 0; r < 4; ++r) {
    int mm = mrow + r;
    if (mm >= Mtot) continue;
    float* dst = part + ((size_t)seg * Mtot + mm) * NCOMB + l15;
#pragma unroll
    for (int ni = 0; ni < 3; ++ni) dst[ni * 16] = acc[ni][r];
  }
}

// -------------------- bilinear sample of combined-map channel (3 K-segments)
__device__ __forceinline__ float samp48(const float* __restrict__ part,
                                        int Mtot, int nbase, int W, int H,
                                        float px, float py, int ch) {
  float xc = fminf(fmaxf(px, 0.f), (float)(W - 1));
  float yc = fminf(fmaxf(py, 0.f), (float)(H - 1));
  float x0f = floorf(xc), y0f = floorf(yc);
  float fx = xc - x0f, fy = yc - y0f;
  int x0 = (int)x0f, y0 = (int)y0f;
  int x1 = min(x0 + 1, W - 1), y1 = min(y0 + 1, H - 1);
  size_t m00 = (size_t)(nbase + y0 * W + x0);
  size_t m01 = (size_t)(nbase + y0 * W + x1);
  size_t m10 = (size_t)(nbase + y1 * W + x0);
  size_t m11 = (size_t)(nbase + y1 * W + x1);
  float v00 = 0.f, v01 = 0.f, v10 = 0.f, v11 = 0.f;
#pragma unroll
  for (int s = 0; s < 3; ++s) {
    size_t off = (size_t)s * Mtot;
    v00 += part[(off + m00) * NCOMB + ch];
    v01 += part[(off + m01) * NCOMB + ch];
    v10 += part[(off + m10) * NCOMB + ch];
    v11 += part[(off + m11) * NCOMB + ch];
  }
  return v00 * (1.f - fx) * (1.f - fy) + v01 * fx * (1.f - fy) +
         v10 * (1.f - fx) * fy + v11 * fx * fy;
}

// ---------------- decode, both levels fused (bx<60 -> L0, else L1)
// emits per-point gather descriptors: sidx int4{base,dx_off,dy_off,-} (bf16 elem
// units, incl. pt*80) + swt float4{w00,w01,w10,w11}, layout [pt][Mtot]
__global__ __launch_bounds__(256) void decode(
    const float* __restrict__ part0, const float* __restrict__ part1,
    const float* __restrict__ dyn_b, const float* __restrict__ anchor0,
    const float* __restrict__ anchor1, float* __restrict__ out_coarse0,
    float* __restrict__ out_coarse1, float* __restrict__ out_regbox0,
    float* __restrict__ out_regbox1, int4* __restrict__ sidx0,
    float4* __restrict__ swt0, int4* __restrict__ sidx1,
    float4* __restrict__ swt1) {
  int bx = blockIdx.x;
  int n = blockIdx.y;
  const float* part;
  const float* anchor;
  float* out_coarse;
  float* out_regbox;
  int4* sidx;
  float4* swt;
  int Mtot, H, W, P, level;
  if (bx < 60) {
    part = part0; anchor = anchor0; out_coarse = out_coarse0;
    out_regbox = out_regbox0; sidx = sidx0; swt = swt0;
    Mtot = M0c; H = 100; W = 152; P = P0c; level = 0;
  } else {
    bx -= 60;
    part = part1; anchor = anchor1; out_coarse = out_coarse1;
    out_regbox = out_regbox1; sidx = sidx1; swt = swt1;
    Mtot = M1c; H = 50; W = 76; P = P1c; level = 1;
  }
  int p = bx * 256 + threadIdx.x;
  if (p >= P) return;
  int m = n * P + p;
  float pr[38];
  {
    const float* q0 = part + (size_t)m * NCOMB;
    const float* q1 = part + ((size_t)Mtot + m) * NCOMB;
    const float* q2 = part + ((size_t)2 * Mtot + m) * NCOMB;
#pragma unroll
    for (int o = 0; o < 38; ++o) pr[o] = q0[o] + q1[o] + q2[o];
#pragma unroll
    for (int o = 0; o < DYN_CH; ++o) pr[o] += dyn_b[o];
  }
  const float* an = anchor + (size_t)n * 4 * P + p;
  float cb[4];
#pragma unroll
  for (int k = 0; k < 4; ++k) cb[k] = an[(size_t)k * P] + pr[k];
  float* oc = out_coarse + (size_t)n * 4 * P + p;
#pragma unroll
  for (int k = 0; k < 4; ++k) oc[(size_t)k * P] = cb[k];

  float thr_y = (cb[3] - cb[1]) * 0.25f;
  float thr_x = (cb[2] - cb[0]) * 0.25f;
  float bo[4];
#pragma unroll
  for (int j = 0; j < 4; ++j) {
    float thr = (j & 1) ? thr_x : thr_y;
    float b = pr[4 + j];
    float extra = fmaxf(b - thr, 0.f) + fminf(b + thr, 0.f);
    bo[j] = b - extra;
  }
  float cx = 0.5f * (cb[0] + cb[2]);
  float cy = 0.5f * (cb[1] + cb[3]);
  float bp[8] = {cb[0], cy + bo[0], cx + bo[1], cb[1],
                 cb[2], cy + bo[2], cx + bo[3], cb[3]};

  int nbase = n * P;
  int nbaseLo = n * P0c;
  float rb[4];
#pragma unroll
  for (int pt = 0; pt < 4; ++pt) {
    float hi = samp48(part, Mtot, nbase, W, H, bp[2 * pt], bp[2 * pt + 1],
                      DYN_CH + pt);
    float val;
    if (level == 0) {
      val = hi;
    } else {
      float lo = 0.5f * samp48(part0, M0c, nbaseLo, 152, 100, bp[2 * pt] * 2.f,
                               bp[2 * pt + 1] * 2.f, DYN_CH + pt);
      float e0 = pr[26 + 2 * pt], e1 = pr[26 + 2 * pt + 1];
      float mx = fmaxf(e0, e1);
      float w0 = expf(e0 - mx), w1 = expf(e1 - mx);
      val = (lo * w0 + hi * w1) / (w0 + w1);
    }
    rb[pt] = val;
  }
  float* orb = out_regbox + (size_t)n * 4 * P + p;
  orb[0] = bp[0] + rb[0];
  orb[(size_t)P] = bp[3] + rb[1];
  orb[(size_t)2 * P] = bp[4] + rb[2];
  orb[(size_t)3 * P] = bp[7] + rb[3];

  float sx[9] = {cb[0], cb[0], cb[0], cx, cx, cx, cb[2], cb[2], cb[2]};
  float sy[9] = {cb[1], cy, cb[3], cb[1], cy, cb[3], cb[1], cy, cb[3]};
#pragma unroll
  for (int k = 0; k < 9; ++k) {
    float px = sx[k] + pr[8 + 2 * k];
    float py = sy[k] + pr[8 + 2 * k + 1];
    float xc = fminf(fmaxf(px, 0.f), (float)(W - 1));
    float yc = fminf(fmaxf(py, 0.f), (float)(H - 1));
    float x0f = floorf(xc), y0f = floorf(yc);
    float fx = xc - x0f, fy = yc - y0f;
    int x0 = (int)x0f, y0 = (int)y0f;
    int x1 = min(x0 + 1, W - 1), y1 = min(y0 + 1, H - 1);
    int4 iv;
    iv.x = (nbase + y0 * W + x0) * CLS_CH + k * 80;
    iv.y = (x1 - x0) * CLS_CH;
    iv.z = (y1 - y0) * W * CLS_CH;
    iv.w = 0;
    sidx[(size_t)k * Mtot + m] = iv;
    float4 wv = {(1.f - fx) * (1.f - fy), fx * (1.f - fy), (1.f - fx) * fy,
                 fx * fy};
    swt[(size_t)k * Mtot + m] = wv;
  }
}

// ------------- gather: wave = 1 px; lanes 0..39 own class pair (2l,2l+1)
// descriptors precomputed by decode; dword bf16x2 taps; stride-5 LDS transpose
__global__ __launch_bounds__(256) void cls_gather_f(
    const __hip_bfloat16* __restrict__ map0,
    const __hip_bfloat16* __restrict__ map1, const int4* __restrict__ sidx0,
    const float4* __restrict__ swt0, const int4* __restrict__ sidx1,
    const float4* __restrict__ swt1, const float* __restrict__ bias,
    float* __restrict__ outc0, float* __restrict__ outc1) {
  __shared__ float lds[NUM_CLASSES * 5];
  int b = (blockIdx.x & 7) * 1188 + (blockIdx.x >> 3);
  if (b >= 9500) return;
  const __hip_bfloat16* map;
  const int4* sidx;
  const float4* swt;
  float* out;
  int Mtot, P;
  if (b < 7600) { map = map0; sidx = sidx0; swt = swt0; out = outc0; Mtot = M0c; P = P0c; }
  else { b -= 7600; map = map1; sidx = sidx1; swt = swt1; out = outc1; Mtot = M1c; P = P1c; }
  int lane = threadIdx.x & 63;
  int wv = threadIdx.x >> 6;
  int m = b * 4 + wv;  // P,M div by 4: no tail, no n-straddle per block

  if (lane < 40) {
    int c2 = lane * 2;
    float ax = 0.f, ay = 0.f;
#pragma unroll
    for (int pt = 0; pt < 9; ++pt) {
      int4 iv = sidx[(size_t)pt * Mtot + m];     // broadcast (wave-uniform)
      float4 wt = swt[(size_t)pt * Mtot + m];
      const __hip_bfloat16* pl = map + iv.x + c2;
      unsigned t00 = *(const unsigned*)(pl);
      unsigned t01 = *(const unsigned*)(pl + iv.y);
      unsigned t10 = *(const unsigned*)(pl + iv.z);
      unsigned t11 = *(const unsigned*)(pl + iv.y + iv.z);
      ax += wt.x * __uint_as_float(t00 << 16) +
            wt.y * __uint_as_float(t01 << 16) +
            wt.z * __uint_as_float(t10 << 16) +
            wt.w * __uint_as_float(t11 << 16);
      ay += wt.x * __uint_as_float(t00 & 0xffff0000u) +
            wt.y * __uint_as_float(t01 & 0xffff0000u) +
            wt.z * __uint_as_float(t10 & 0xffff0000u) +
            wt.w * __uint_as_float(t11 & 0xffff0000u);
    }
    lds[c2 * 5 + wv] = ax;
    lds[(c2 + 1) * 5 + wv] = ay;
  }
  __syncthreads();
  int tid = threadIdx.x;
  if (tid < NUM_CLASSES) {
    float bb = bias[tid];
    float4 v = {lds[tid * 5] + bb, lds[tid * 5 + 1] + bb, lds[tid * 5 + 2] + bb,
                lds[tid * 5 + 3] + bb};
    int m0 = b * 4;
    int n = m0 / P;
    int p0 = m0 - n * P;
    *(float4*)&out[((size_t)n * NUM_CLASSES + tid) * P + p0] = v;
  }
}

// ---------------------------------------------------------------------- launch
extern "C" void kernel_launch(void* const* d_in, const int* in_sizes, int n_in,
                              void* d_out, int out_size, void* d_ws,
                              size_t ws_size, hipStream_t stream) {
  const float* reg_feat0 = (const float*)d_in[0];
  const float* reg_feat1 = (const float*)d_in[1];
  const float* cls_feat0 = (const float*)d_in[2];
  const float* cls_feat1 = (const float*)d_in[3];
  const float* anchor0 = (const float*)d_in[4];
  const float* anchor1 = (const float*)d_in[5];
  const float* dyn_w = (const float*)d_in[6];
  const float* dyn_b = (const float*)d_in[7];
  const float* reg_w = (const float*)d_in[8];
  const float* cls_w = (const float*)d_in[9];
  const float* cls_b = (const float*)d_in[10];

  float* out = (float*)d_out;
  float* out_cls0 = out;
  float* out_cls1 = out_cls0 + (size_t)N_BATCH * NUM_CLASSES * P0c;
  float* out_coarse0 = out_cls1 + (size_t)N_BATCH * NUM_CLASSES * P1c;
  float* out_coarse1 = out_coarse0 + (size_t)N_BATCH * 4 * P0c;
  float* out_reg0 = out_coarse1 + (size_t)N_BATCH * 4 * P1c;
  float* out_reg1 = out_reg0 + (size_t)N_BATCH * 4 * P0c;

  // ---- workspace layout (bytes)
  char* w = (char*)d_ws;
  __hip_bfloat16* bpack = (__hip_bfloat16*)w;   w += 368640;
  __hip_bfloat16* wpack = (__hip_bfloat16*)w;   w += 221184;
  char* apack_base = w;
  __hip_bfloat16* apack0 = (__hip_bfloat16*)w;  w += 15597568;  // 119*8192*16
  __hip_bfloat16* apack1 = (__hip_bfloat16*)w;  w += 3932160;   // 30*8192*16
  char* rpack_base = w;
  __hip_bfloat16* rpack0 = (__hip_bfloat16*)w;  w += 15597568;  // tiled
  __hip_bfloat16* rpack1 = (__hip_bfloat16*)w;  w += 3932160;
  float* part1 = (float*)w;                     w += 4377600;   // 3*M1*48*4
  __hip_bfloat16* map0 = (__hip_bfloat16*)w;    w += 43776000;  // M0*720*2
  __hip_bfloat16* map1 = (__hip_bfloat16*)w;    w += 10944000;  // M1*720*2
  // part0 (17510400 B) aliases apack0+apack1 (dead after gemm).
  float* part0 = (float*)apack_base;
  // gather descriptors alias rpack0+rpack1 (19.5 MB, dead after conv):
  // sidx0 4377600 + swt0 4377600 + sidx1 1094400 + swt1 1094400 = 10.9 MB
  int4* sidx0 = (int4*)rpack_base;
  float4* swt0 = (float4*)(rpack_base + 4377600);
  int4* sidx1 = (int4*)(rpack_base + 8755200);
  float4* swt1 = (float4*)(rpack_base + 9849600);

  hipLaunchKernelGGL(pack_feat, dim3(2528), dim3(256), 0, stream, cls_feat0,
                     cls_feat1, reg_feat0, reg_feat1, cls_w, dyn_w, reg_w,
                     apack0, apack1, rpack0, rpack1, bpack, wpack);
  hipLaunchKernelGGL(cls_gemm_mfma, dim3(MT0c + MT1c, 9), dim3(256), 0, stream,
                     (const uint4*)apack0, (const uint4*)apack1,
                     (const uint4*)bpack, map0, map1);
  hipLaunchKernelGGL(dyn_reg_conv_mfma, dim3(CT0c + CT1c, 3), dim3(256), 0,
                     stream, (const uint4*)rpack0, (const uint4*)rpack1,
                     (const uint4*)wpack, part0, part1);
  hipLaunchKernelGGL(decode, dim3(75, N_BATCH), dim3(256), 0, stream, part0,
                     part1, dyn_b, anchor0, anchor1, out_coarse0, out_coarse1,
                     out_reg0, out_reg1, sidx0, swt0, sidx1, swt1);
  hipLaunchKernelGGL(cls_gather_f, dim3(9504), dim3(256), 0, stream, map0,
                     map1, sidx0, swt0, sidx1, swt1, cls_b, out_cls0, out_cls1);
}

// Round 9
// 244.491 us; speedup vs baseline: 1.5630x; 1.0571x over previous
//
#include <hip/hip_runtime.h>
#include <hip/hip_bf16.h>
#include <cstdint>

#define N_BATCH 2
#define C_IN 256
#define DYN_CH 34
#define CLS_CH 720
#define NUM_CLASSES 80
#define NCOMB 48

#define P0c 15200
#define P1c 3800
#define M0c 30400
#define M1c 7600
#define MT0c 119
#define MT1c 30
#define CT0c 475
#define CT1c 119

typedef __attribute__((ext_vector_type(8))) short short8;   // 8 bf16
typedef __attribute__((ext_vector_type(4))) float f32x4;

typedef const unsigned int __attribute__((address_space(1)))* gas1_t;
typedef unsigned int __attribute__((address_space(3)))* las3_t;

__device__ __forceinline__ void async_ld16(const void* g, void* l) {
  __builtin_amdgcn_global_load_lds((gas1_t)g, (las3_t)l, 16, 0, 0);
}

// ---------------- pack_feat: all 4 feature packs (tiled layout) + weight packs
__global__ __launch_bounds__(256) void pack_feat(
    const float* __restrict__ cls0, const float* __restrict__ cls1,
    const float* __restrict__ reg0, const float* __restrict__ reg1,
    const float* __restrict__ cls_w, const float* __restrict__ dyn_w,
    const float* __restrict__ reg_w, __hip_bfloat16* __restrict__ a0,
    __hip_bfloat16* __restrict__ a1, __hip_bfloat16* __restrict__ r0,
    __hip_bfloat16* __restrict__ r1, __hip_bfloat16* __restrict__ bpack,
    __hip_bfloat16* __restrict__ wpack) {
  int b = blockIdx.x;
  if (b >= 2384) {
    b -= 2384;
    if (b < 90) {  // cls weights -> bpack [ntile][kcg][och]
      int u = b * 256 + threadIdx.x;
      if (u >= 9 * 32 * 80) return;
      int ntile = u / 2560;
      int rem = u % 2560;
      int kcg = rem / 80;
      int ochl = rem % 80;
      int och = ntile * 80 + ochl;
      const float* wr = cls_w + (size_t)och * C_IN + kcg * 8;
      __hip_bfloat16 tmp[8];
#pragma unroll
      for (int c = 0; c < 8; ++c) tmp[c] = __float2bfloat16(wr[c]);
      *(uint4*)(bpack + (size_t)u * 8) = *(const uint4*)tmp;
    } else {  // dyn+reg weights -> wpack swizzled [chunk][n][slot]
      int u = (b - 90) * 256 + threadIdx.x;
      if (u >= 13824) return;
      int j = u / 768;
      int r = u % 768;
      int n = r / 16;
      int s = r % 16;
      int ku = j * 16 + (s ^ (n & 7));
      int k0 = ku * 8;
      int tap = k0 >> 8;
      int c0 = k0 & 255;
      __hip_bfloat16 tmp[8];
#pragma unroll
      for (int i = 0; i < 8; ++i) {
        int c = c0 + i;
        float v = 0.f;
        if (n < DYN_CH) v = dyn_w[((size_t)n * C_IN + c) * 9 + tap];
        else if (n < DYN_CH + 4 && tap == 4)
          v = reg_w[(size_t)(n - DYN_CH) * C_IN + c];
        tmp[i] = __float2bfloat16(v);
      }
      *(uint4*)(wpack + (size_t)u * 8) = *(const uint4*)tmp;
    }
    return;
  }
  int j = b & 7;
  int mtg = b >> 3;
  const float* src;
  __hip_bfloat16* dst;
  int P, Mtot, mtile;
  if (mtg < 119)      { src = cls0; dst = a0; P = P0c; Mtot = M0c; mtile = mtg; }
  else if (mtg < 149) { src = cls1; dst = a1; P = P1c; Mtot = M1c; mtile = mtg - 119; }
  else if (mtg < 268) { src = reg0; dst = r0; P = P0c; Mtot = M0c; mtile = mtg - 149; }
  else                { src = reg1; dst = r1; P = P1c; Mtot = M1c; mtile = mtg - 268; }
  int wave = threadIdx.x >> 6;
  int lane = threadIdx.x & 63;
  int kcg = j * 4 + wave;
  int c0 = kcg * 8;
  int m4 = mtile * 256 + lane * 4;
  uint4* du = (uint4*)dst + (size_t)mtile * 8192 + (size_t)kcg * 256 + lane * 4;
  if (m4 < Mtot) {
    int n = m4 / P;
    int p = m4 - n * P;
    const float* sp = src + ((size_t)n * C_IN + c0) * P + p;
    float4 f[8];
#pragma unroll
    for (int c = 0; c < 8; ++c) f[c] = *(const float4*)(sp + (size_t)c * P);
#pragma unroll
    for (int i = 0; i < 4; ++i) {
      union { uint4 u; __hip_bfloat16 h[8]; } o;
#pragma unroll
      for (int c = 0; c < 8; ++c) {
        float v = (i == 0) ? f[c].x : (i == 1) ? f[c].y : (i == 2) ? f[c].z : f[c].w;
        o.h[c] = __float2bfloat16(v);
      }
      du[i] = o.u;
    }
  } else {
    uint4 z = {0u, 0u, 0u, 0u};
#pragma unroll
    for (int i = 0; i < 4; ++i) du[i] = z;
  }
}

// ------------------- cls 1x1 bf16 MFMA GEMM -> bf16 map pixel-major [m][720]
// XCD-aware 1-D grid: g=b&7 owns mtiles [g*19,g*19+19); the 9 ntile-blocks of
// one mtile are consecutive on that XCD -> A-slab fetched once per XCD L2.
__global__ __launch_bounds__(256) void cls_gemm_mfma(
    const uint4* __restrict__ Ap0, const uint4* __restrict__ Ap1,
    const uint4* __restrict__ Bp, __hip_bfloat16* __restrict__ out0,
    __hip_bfloat16* __restrict__ out1) {
  __shared__ uint4 Ash[1024];
  __shared__ uint4 Bsh[320];
  int bb = blockIdx.x;
  int g = bb & 7;
  int loc = bb >> 3;          // [0,171) = 19 mtiles x 9 ntiles
  int lm = loc / 9;
  int ntile = loc - lm * 9;
  int mtile = g * 19 + lm;
  if (mtile >= MT0c + MT1c) return;
  int tid = threadIdx.x;
  int wave = tid >> 6;
  int lane = tid & 63;
  int l15 = lane & 15;
  int kq = lane >> 4;

  const uint4* Ap;
  __hip_bfloat16* out;
  int Mtot;
  if (mtile < MT0c) { Ap = Ap0; out = out0; Mtot = M0c; }
  else              { mtile -= MT0c; Ap = Ap1; out = out1; Mtot = M1c; }

  const uint4* Ab = Ap + (size_t)mtile * 8192;
  const uint4* Bb = Bp + (size_t)ntile * 2560;

  f32x4 acc[4][5];
#pragma unroll
  for (int i = 0; i < 4; ++i)
#pragma unroll
    for (int j = 0; j < 5; ++j) acc[i][j] = (f32x4)0.f;

  for (int kb = 0; kb < 8; ++kb) {
    const uint4* Aslab = Ab + kb * 1024;
#pragma unroll
    for (int i = 0; i < 4; ++i) {
      int j = wave * 4 + i;
      async_ld16(Aslab + j * 64 + lane, &Ash[j * 64]);
    }
    const uint4* Bslab = Bb + kb * 320;
    for (int j = wave; j < 5; j += 4) {
      async_ld16(Bslab + j * 64 + lane, &Bsh[j * 64]);
    }
    __syncthreads();

    short8 a[4], b[5];
    const uint4* Ar = &Ash[kq * 256 + wave * 64 + l15];
#pragma unroll
    for (int mi = 0; mi < 4; ++mi) a[mi] = *(const short8*)&Ar[mi * 16];
    const uint4* Br = &Bsh[kq * 80 + l15];
#pragma unroll
    for (int ni = 0; ni < 5; ++ni) b[ni] = *(const short8*)&Br[ni * 16];
#pragma unroll
    for (int mi = 0; mi < 4; ++mi)
#pragma unroll
      for (int ni = 0; ni < 5; ++ni)
        acc[mi][ni] = __builtin_amdgcn_mfma_f32_16x16x32_bf16(
            a[mi], b[ni], acc[mi][ni], 0, 0, 0);
    __syncthreads();
  }

  int gbase = mtile * 256 + wave * 64;
#pragma unroll
  for (int mi = 0; mi < 4; ++mi) {
#pragma unroll
    for (int r = 0; r < 4; ++r) {
      int gg = gbase + mi * 16 + kq * 4 + r;
      if (gg >= Mtot) continue;
      __hip_bfloat16* orow = out + (size_t)gg * CLS_CH + ntile * 80 + l15;
#pragma unroll
      for (int ni = 0; ni < 5; ++ni)
        orow[ni * 16] = __float2bfloat16(acc[mi][ni][r]);
    }
  }
}

// ---------- dyn3x3 + reg1x1 fused implicit-GEMM MFMA, split-K=3, both levels
__global__ __launch_bounds__(256) void dyn_reg_conv_mfma(
    const uint4* __restrict__ rp0, const uint4* __restrict__ rp1,
    const uint4* __restrict__ wp, float* __restrict__ part0,
    float* __restrict__ part1) {
  __shared__ uint4 Bs[768];
  int tid = threadIdx.x;
  int wave = tid >> 6;
  int lane = tid & 63;
  int l15 = lane & 15;
  int kq = lane >> 4;
  int seg = blockIdx.y;
  int bx = blockIdx.x;

  const uint4* rp;
  float* part;
  int Mtot, P, W, H;
  if (bx < CT0c) { rp = rp0; part = part0; Mtot = M0c; P = P0c; W = 152; H = 100; }
  else { bx -= CT0c; rp = rp1; part = part1; Mtot = M1c; P = P1c; W = 76; H = 50; }

  int m = bx * 64 + wave * 16 + l15;
  bool mval = (m < Mtot);
  int mc = mval ? m : 0;
  int n = mc / P;
  int rem = mc - n * P;
  int y = rem / W;
  int x = rem - y * W;

  f32x4 acc[3];
#pragma unroll
  for (int i = 0; i < 3; ++i) acc[i] = (f32x4)0.f;

  for (int jj = 0; jj < 6; ++jj) {
    int j = seg * 6 + jj;
    const uint4* wsrc = wp + (size_t)j * 768 + wave * 192;
#pragma unroll
    for (int i = 0; i < 3; ++i)
      async_ld16(wsrc + i * 64 + lane, &Bs[wave * 192 + i * 64]);

    int tap = j >> 1;
    int cb8 = (j & 1) * 16;
    int dy = tap / 3 - 1, dx = tap % 3 - 1;
    int sy = y + dy, sx = x + dx;
    bool val = mval && ((unsigned)sy < (unsigned)H) && ((unsigned)sx < (unsigned)W);
    int sm = m + dy * W + dx;
    int smc = val ? sm : 0;
    size_t tbase = (size_t)(smc >> 8) * 8192 + (smc & 255);
    uint4 a[4];
#pragma unroll
    for (int t = 0; t < 4; ++t) {
      uint4 v = {0u, 0u, 0u, 0u};
      if (val) v = rp[tbase + (size_t)(cb8 + t * 4 + kq) * 256];
      a[t] = v;
    }
    __syncthreads();
#pragma unroll
    for (int t = 0; t < 4; ++t) {
#pragma unroll
      for (int ni = 0; ni < 3; ++ni) {
        int nn = ni * 16 + l15;
        short8 bf = *(const short8*)&Bs[nn * 16 + ((t * 4 + kq) ^ (nn & 7))];
        acc[ni] = __builtin_amdgcn_mfma_f32_16x16x32_bf16(
            *(short8*)&a[t], bf, acc[ni], 0, 0, 0);
      }
    }
    __syncthreads();
  }

  int mrow = bx * 64 + wave * 16 + kq * 4;
#pragma unroll
  for (int r = 0; r < 4; ++r) {
    int mm = mrow + r;
    if (mm >= Mtot) continue;
    float* dst = part + ((size_t)seg * Mtot + mm) * NCOMB + l15;
#pragma unroll
    for (int ni = 0; ni < 3; ++ni) dst[ni * 16] = acc[ni][r];
  }
}

// -------------------- bilinear sample of combined-map channel (3 K-segments)
__device__ __forceinline__ float samp48(const float* __restrict__ part,
                                        int Mtot, int nbase, int W, int H,
                                        float px, float py, int ch) {
  float xc = fminf(fmaxf(px, 0.f), (float)(W - 1));
  float yc = fminf(fmaxf(py, 0.f), (float)(H - 1));
  float x0f = floorf(xc), y0f = floorf(yc);
  float fx = xc - x0f, fy = yc - y0f;
  int x0 = (int)x0f, y0 = (int)y0f;
  int x1 = min(x0 + 1, W - 1), y1 = min(y0 + 1, H - 1);
  size_t m00 = (size_t)(nbase + y0 * W + x0);
  size_t m01 = (size_t)(nbase + y0 * W + x1);
  size_t m10 = (size_t)(nbase + y1 * W + x0);
  size_t m11 = (size_t)(nbase + y1 * W + x1);
  float v00 = 0.f, v01 = 0.f, v10 = 0.f, v11 = 0.f;
#pragma unroll
  for (int s = 0; s < 3; ++s) {
    size_t off = (size_t)s * Mtot;
    v00 += part[(off + m00) * NCOMB + ch];
    v01 += part[(off + m01) * NCOMB + ch];
    v10 += part[(off + m10) * NCOMB + ch];
    v11 += part[(off + m11) * NCOMB + ch];
  }
  return v00 * (1.f - fx) * (1.f - fy) + v01 * fx * (1.f - fy) +
         v10 * (1.f - fx) * fy + v11 * fx * fy;
}

// ---------------- decode, both levels fused (bx<60 -> L0, else L1)
// emits per-point gather descriptors: sidx int4{base,dx_off,dy_off,-} + swt
__global__ __launch_bounds__(256) void decode(
    const float* __restrict__ part0, const float* __restrict__ part1,
    const float* __restrict__ dyn_b, const float* __restrict__ anchor0,
    const float* __restrict__ anchor1, float* __restrict__ out_coarse0,
    float* __restrict__ out_coarse1, float* __restrict__ out_regbox0,
    float* __restrict__ out_regbox1, int4* __restrict__ sidx0,
    float4* __restrict__ swt0, int4* __restrict__ sidx1,
    float4* __restrict__ swt1) {
  int bx = blockIdx.x;
  int n = blockIdx.y;
  const float* part;
  const float* anchor;
  float* out_coarse;
  float* out_regbox;
  int4* sidx;
  float4* swt;
  int Mtot, H, W, P, level;
  if (bx < 60) {
    part = part0; anchor = anchor0; out_coarse = out_coarse0;
    out_regbox = out_regbox0; sidx = sidx0; swt = swt0;
    Mtot = M0c; H = 100; W = 152; P = P0c; level = 0;
  } else {
    bx -= 60;
    part = part1; anchor = anchor1; out_coarse = out_coarse1;
    out_regbox = out_regbox1; sidx = sidx1; swt = swt1;
    Mtot = M1c; H = 50; W = 76; P = P1c; level = 1;
  }
  int p = bx * 256 + threadIdx.x;
  if (p >= P) return;
  int m = n * P + p;
  float pr[38];
  {
    const float* q0 = part + (size_t)m * NCOMB;
    const float* q1 = part + ((size_t)Mtot + m) * NCOMB;
    const float* q2 = part + ((size_t)2 * Mtot + m) * NCOMB;
#pragma unroll
    for (int o = 0; o < 38; ++o) pr[o] = q0[o] + q1[o] + q2[o];
#pragma unroll
    for (int o = 0; o < DYN_CH; ++o) pr[o] += dyn_b[o];
  }
  const float* an = anchor + (size_t)n * 4 * P + p;
  float cb[4];
#pragma unroll
  for (int k = 0; k < 4; ++k) cb[k] = an[(size_t)k * P] + pr[k];
  float* oc = out_coarse + (size_t)n * 4 * P + p;
#pragma unroll
  for (int k = 0; k < 4; ++k) oc[(size_t)k * P] = cb[k];

  float thr_y = (cb[3] - cb[1]) * 0.25f;
  float thr_x = (cb[2] - cb[0]) * 0.25f;
  float bo[4];
#pragma unroll
  for (int j = 0; j < 4; ++j) {
    float thr = (j & 1) ? thr_x : thr_y;
    float b = pr[4 + j];
    float extra = fmaxf(b - thr, 0.f) + fminf(b + thr, 0.f);
    bo[j] = b - extra;
  }
  float cx = 0.5f * (cb[0] + cb[2]);
  float cy = 0.5f * (cb[1] + cb[3]);
  float bp[8] = {cb[0], cy + bo[0], cx + bo[1], cb[1],
                 cb[2], cy + bo[2], cx + bo[3], cb[3]};

  int nbase = n * P;
  int nbaseLo = n * P0c;
  float rb[4];
#pragma unroll
  for (int pt = 0; pt < 4; ++pt) {
    float hi = samp48(part, Mtot, nbase, W, H, bp[2 * pt], bp[2 * pt + 1],
                      DYN_CH + pt);
    float val;
    if (level == 0) {
      val = hi;
    } else {
      float lo = 0.5f * samp48(part0, M0c, nbaseLo, 152, 100, bp[2 * pt] * 2.f,
                               bp[2 * pt + 1] * 2.f, DYN_CH + pt);
      float e0 = pr[26 + 2 * pt], e1 = pr[26 + 2 * pt + 1];
      float mx = fmaxf(e0, e1);
      float w0 = expf(e0 - mx), w1 = expf(e1 - mx);
      val = (lo * w0 + hi * w1) / (w0 + w1);
    }
    rb[pt] = val;
  }
  float* orb = out_regbox + (size_t)n * 4 * P + p;
  orb[0] = bp[0] + rb[0];
  orb[(size_t)P] = bp[3] + rb[1];
  orb[(size_t)2 * P] = bp[4] + rb[2];
  orb[(size_t)3 * P] = bp[7] + rb[3];

  float sx[9] = {cb[0], cb[0], cb[0], cx, cx, cx, cb[2], cb[2], cb[2]};
  float sy[9] = {cb[1], cy, cb[3], cb[1], cy, cb[3], cb[1], cy, cb[3]};
#pragma unroll
  for (int k = 0; k < 9; ++k) {
    float px = sx[k] + pr[8 + 2 * k];
    float py = sy[k] + pr[8 + 2 * k + 1];
    float xc = fminf(fmaxf(px, 0.f), (float)(W - 1));
    float yc = fminf(fmaxf(py, 0.f), (float)(H - 1));
    float x0f = floorf(xc), y0f = floorf(yc);
    float fx = xc - x0f, fy = yc - y0f;
    int x0 = (int)x0f, y0 = (int)y0f;
    int x1 = min(x0 + 1, W - 1), y1 = min(y0 + 1, H - 1);
    int4 iv;
    iv.x = (nbase + y0 * W + x0) * CLS_CH + k * 80;
    iv.y = (x1 - x0) * CLS_CH;
    iv.z = (y1 - y0) * W * CLS_CH;
    iv.w = 0;
    sidx[(size_t)k * Mtot + m] = iv;
    float4 wv = {(1.f - fx) * (1.f - fy), fx * (1.f - fy), (1.f - fx) * fy,
                 fx * fy};
    swt[(size_t)k * Mtot + m] = wv;
  }
}

// ------------- gather: wave = 1 px; lanes 0..39 own class pair (2l,2l+1)
__global__ __launch_bounds__(256) void cls_gather_f(
    const __hip_bfloat16* __restrict__ map0,
    const __hip_bfloat16* __restrict__ map1, const int4* __restrict__ sidx0,
    const float4* __restrict__ swt0, const int4* __restrict__ sidx1,
    const float4* __restrict__ swt1, const float* __restrict__ bias,
    float* __restrict__ outc0, float* __restrict__ outc1) {
  __shared__ float lds[NUM_CLASSES * 5];
  int b = (blockIdx.x & 7) * 1188 + (blockIdx.x >> 3);
  if (b >= 9500) return;
  const __hip_bfloat16* map;
  const int4* sidx;
  const float4* swt;
  float* out;
  int Mtot, P;
  if (b < 7600) { map = map0; sidx = sidx0; swt = swt0; out = outc0; Mtot = M0c; P = P0c; }
  else { b -= 7600; map = map1; sidx = sidx1; swt = swt1; out = outc1; Mtot = M1c; P = P1c; }
  int lane = threadIdx.x & 63;
  int wv = threadIdx.x >> 6;
  int m = b * 4 + wv;  // P,M div by 4: no tail, no n-straddle per block

  if (lane < 40) {
    int c2 = lane * 2;
    float ax = 0.f, ay = 0.f;
#pragma unroll
    for (int pt = 0; pt < 9; ++pt) {
      int4 iv = sidx[(size_t)pt * Mtot + m];     // broadcast (wave-uniform)
      float4 wt = swt[(size_t)pt * Mtot + m];
      const __hip_bfloat16* pl = map + iv.x + c2;
      unsigned t00 = *(const unsigned*)(pl);
      unsigned t01 = *(const unsigned*)(pl + iv.y);
      unsigned t10 = *(const unsigned*)(pl + iv.z);
      unsigned t11 = *(const unsigned*)(pl + iv.y + iv.z);
      ax += wt.x * __uint_as_float(t00 << 16) +
            wt.y * __uint_as_float(t01 << 16) +
            wt.z * __uint_as_float(t10 << 16) +
            wt.w * __uint_as_float(t11 << 16);
      ay += wt.x * __uint_as_float(t00 & 0xffff0000u) +
            wt.y * __uint_as_float(t01 & 0xffff0000u) +
            wt.z * __uint_as_float(t10 & 0xffff0000u) +
            wt.w * __uint_as_float(t11 & 0xffff0000u);
    }
    lds[c2 * 5 + wv] = ax;
    lds[(c2 + 1) * 5 + wv] = ay;
  }
  __syncthreads();
  int tid = threadIdx.x;
  if (tid < NUM_CLASSES) {
    float bb = bias[tid];
    float4 v = {lds[tid * 5] + bb, lds[tid * 5 + 1] + bb, lds[tid * 5 + 2] + bb,
                lds[tid * 5 + 3] + bb};
    int m0 = b * 4;
    int n = m0 / P;
    int p0 = m0 - n * P;
    *(float4*)&out[((size_t)n * NUM_CLASSES + tid) * P + p0] = v;
  }
}

// ---------------------------------------------------------------------- launch
extern "C" void kernel_launch(void* const* d_in, const int* in_sizes, int n_in,
                              void* d_out, int out_size, void* d_ws,
                              size_t ws_size, hipStream_t stream) {
  const float* reg_feat0 = (const float*)d_in[0];
  const float* reg_feat1 = (const float*)d_in[1];
  const float* cls_feat0 = (const float*)d_in[2];
  const float* cls_feat1 = (const float*)d_in[3];
  const float* anchor0 = (const float*)d_in[4];
  const float* anchor1 = (const float*)d_in[5];
  const float* dyn_w = (const float*)d_in[6];
  const float* dyn_b = (const float*)d_in[7];
  const float* reg_w = (const float*)d_in[8];
  const float* cls_w = (const float*)d_in[9];
  const float* cls_b = (const float*)d_in[10];

  float* out = (float*)d_out;
  float* out_cls0 = out;
  float* out_cls1 = out_cls0 + (size_t)N_BATCH * NUM_CLASSES * P0c;
  float* out_coarse0 = out_cls1 + (size_t)N_BATCH * NUM_CLASSES * P1c;
  float* out_coarse1 = out_coarse0 + (size_t)N_BATCH * 4 * P0c;
  float* out_reg0 = out_coarse1 + (size_t)N_BATCH * 4 * P1c;
  float* out_reg1 = out_reg0 + (size_t)N_BATCH * 4 * P0c;

  // ---- workspace layout (bytes)
  char* w = (char*)d_ws;
  __hip_bfloat16* bpack = (__hip_bfloat16*)w;   w += 368640;
  __hip_bfloat16* wpack = (__hip_bfloat16*)w;   w += 221184;
  char* apack_base = w;
  __hip_bfloat16* apack0 = (__hip_bfloat16*)w;  w += 15597568;  // 119*8192*16
  __hip_bfloat16* apack1 = (__hip_bfloat16*)w;  w += 3932160;   // 30*8192*16
  char* rpack_base = w;
  __hip_bfloat16* rpack0 = (__hip_bfloat16*)w;  w += 15597568;  // tiled
  __hip_bfloat16* rpack1 = (__hip_bfloat16*)w;  w += 3932160;
  float* part1 = (float*)w;                     w += 4377600;   // 3*M1*48*4
  __hip_bfloat16* map0 = (__hip_bfloat16*)w;    w += 43776000;  // M0*720*2
  __hip_bfloat16* map1 = (__hip_bfloat16*)w;    w += 10944000;  // M1*720*2
  // part0 (17510400 B) aliases apack0+apack1 (dead after gemm).
  float* part0 = (float*)apack_base;
  // gather descriptors alias rpack0+rpack1 (19.5 MB, dead after conv)
  int4* sidx0 = (int4*)rpack_base;
  float4* swt0 = (float4*)(rpack_base + 4377600);
  int4* sidx1 = (int4*)(rpack_base + 8755200);
  float4* swt1 = (float4*)(rpack_base + 9849600);

  hipLaunchKernelGGL(pack_feat, dim3(2528), dim3(256), 0, stream, cls_feat0,
                     cls_feat1, reg_feat0, reg_feat1, cls_w, dyn_w, reg_w,
                     apack0, apack1, rpack0, rpack1, bpack, wpack);
  hipLaunchKernelGGL(cls_gemm_mfma, dim3(8 * 19 * 9), dim3(256), 0, stream,
                     (const uint4*)apack0, (const uint4*)apack1,
                     (const uint4*)bpack, map0, map1);
  hipLaunchKernelGGL(dyn_reg_conv_mfma, dim3(CT0c + CT1c, 3), dim3(256), 0,
                     stream, (const uint4*)rpack0, (const uint4*)rpack1,
                     (const uint4*)wpack, part0, part1);
  hipLaunchKernelGGL(decode, dim3(75, N_BATCH), dim3(256), 0, stream, part0,
                     part1, dyn_b, anchor0, anchor1, out_coarse0, out_coarse1,
                     out_reg0, out_reg1, sidx0, swt0, sidx1, swt1);
  hipLaunchKernelGGL(cls_gather_f, dim3(9504), dim3(256), 0, stream, map0,
                     map1, sidx0, swt0, sidx1, swt1, cls_b, out_cls0, out_cls1);
}